// Round 9
// baseline (2104.924 us; speedup 1.0000x reference)
//
#include <hip/hip_runtime.h>

typedef __attribute__((ext_vector_type(8))) short short8;
typedef __attribute__((ext_vector_type(4))) float f32x4;

#define MFMA16(a, b, c) __builtin_amdgcn_mfma_f32_16x16x32_bf16((a), (b), (c), 0, 0, 0)

constexpr int Bv  = 32;    // batch
constexpr int Lv  = 168;   // encoder length
constexpr int Sv  = 512;   // sites
constexpr int HZv = 24;    // horizon
constexpr int HSTR = 88;   // h-row stride (shorts): 176 B/row -> 16B-aligned b128, bank stride 44%32=12 -> 2-way (free)
constexpr int HBUF = 32 * HSTR;
constexpr int PSTR = 66;   // PRE row stride (f32): 2-way free
constexpr int PG   = 32 * PSTR;

__device__ __forceinline__ float b2f(short s) {
    unsigned u = ((unsigned)(unsigned short)s) << 16;
    return __builtin_bit_cast(float, u);
}
__device__ __forceinline__ short f2b(float f) {
    unsigned u = __builtin_bit_cast(unsigned, f);
    unsigned r = (u + 0x7FFFu + ((u >> 16) & 1u)) >> 16;   // RNE
    return (short)(unsigned short)r;
}
__device__ __forceinline__ float sigm(float x) {
    x = fmaxf(x, -85.0f);
    float e = __builtin_amdgcn_exp2f(-1.44269504088896f * x);
    return __builtin_amdgcn_rcpf(1.0f + e);
}
__device__ __forceinline__ float tanh_(float x) {
    x = fminf(x, 43.0f);
    float e = __builtin_amdgcn_exp2f(2.88539008177793f * x); // exp(2x)
    return 1.0f - 2.0f * __builtin_amdgcn_rcpf(e + 1.0f);
}
__device__ __forceinline__ void split8(const float* __restrict__ p, short8& hi, short8& lo) {
#pragma unroll
    for (int j = 0; j < 8; ++j) {
        float x = p[j];
        short h = f2b(x);
        hi[j] = h;
        lo[j] = f2b(x - b2f(h));
    }
}

// 512-thread block (8 waves), M=32 seqs. Wave w: unit-slice U=w&3, gate-pair P=w>>2.
// LDS 77.4 KB -> 2 blocks/CU co-resident (one pass of 512 blocks).
// VGPR capped 128 via launch_bounds(512,4) (r8 measured 124, no spills).
__global__ __launch_bounds__(512, 4)
void sitewise_lstm(const float* __restrict__ x_seq,
                   const float* __restrict__ Wih0, const float* __restrict__ Whh0,
                   const float* __restrict__ bih0, const float* __restrict__ bhh0,
                   const float* __restrict__ Wih1, const float* __restrict__ Whh1,
                   const float* __restrict__ bih1, const float* __restrict__ bhh1,
                   const float* __restrict__ Wcih, const float* __restrict__ Wchh,
                   const float* __restrict__ bcih, const float* __restrict__ bchh,
                   const float* __restrict__ Wout, const float* __restrict__ bout,
                   float* __restrict__ out)
{
    __shared__ __align__(16) short Hhi[4 * HBUF];   // 22.5 KB
    __shared__ __align__(16) short Hlo[4 * HBUF];   // 22.5 KB
    __shared__ __align__(16) float PRE[4 * PG];     // 33.8 KB preactivation exchange
    __shared__ float woutF[64];
    __shared__ float ybufF[32];

    const int tid  = threadIdx.x;
    const int wv   = tid >> 6;
    const int lane = tid & 63;
    const int q    = lane >> 4;
    const int col  = lane & 15;
    const int U    = wv & 3;      // unit-slice: u in [16U, 16U+16)
    const int P    = wv >> 2;     // MFMA: gates {2P, 2P+1}; epilogue: m-half [16P, 16P+16)
    const int bid  = blockIdx.x;
    const int b    = bid >> 4;
    const int s0   = (bid & 15) << 5;
    const int uu   = U * 16 + col;          // epilogue unit column
    const int me   = P * 16 + q * 4;        // epilogue m base (+r)

    for (int i = tid; i < 4 * HBUF / 2; i += 512) { ((int*)Hhi)[i] = 0; ((int*)Hlo)[i] = 0; }
    if (tid < 64) woutF[tid] = Wout[tid];

    const float* xbF = x_seq + b * Lv * Sv + s0;

    // ---- per-wave weights: 2 gate-tiles per matrix, hi+lo in registers ----
    short8 Whi[3][2][2], Wlo[3][2][2];   // [Whh0|Wih1|Whh1][g2][kc]; slot0 -> Wchh in decoder
    float biasM0[2], biasM1[2], biasMc[2];
    float wih0gE[4], wcihgE[4];
#pragma unroll
    for (int g2 = 0; g2 < 2; ++g2) {
        const int g = 2 * P + g2;
        const int j = g * 64 + U * 16 + col;
        biasM0[g2] = bih0[j] + bhh0[j];
        biasM1[g2] = bih1[j] + bhh1[j];
        biasMc[g2] = bcih[j] + bchh[j];
#pragma unroll
        for (int kc = 0; kc < 2; ++kc) {
            const int off = j * 64 + kc * 32 + q * 8;
            split8(Whh0 + off, Whi[0][g2][kc], Wlo[0][g2][kc]);
            split8(Wih1 + off, Whi[1][g2][kc], Wlo[1][g2][kc]);
            split8(Whh1 + off, Whi[2][g2][kc], Wlo[2][g2][kc]);
        }
    }
#pragma unroll
    for (int g = 0; g < 4; ++g) {
        wih0gE[g] = Wih0[g * 64 + uu];
        wcihgE[g] = Wcih[g * 64 + uu];
    }

    float c0[4], c1[4];
#pragma unroll
    for (int i = 0; i < 4; ++i) { c0[i] = 0.f; c1[i] = 0.f; }

    __syncthreads();

    // ================= encoder =================
    for (int t = 0; t < Lv; ++t) {
        const int p = t & 1, np = p ^ 1;
        const int B0p = p * HBUF, B0n = np * HBUF;
        const int B1p = (2 + p) * HBUF, B1n = (2 + np) * HBUF;

        // issue x load early (consumed in epilogue 0 -> hidden under MFMA phase)
        const f32x4 xv = *(const f32x4*)(xbF + t * Sv + me);

        // ---- phase 1: old-state fragments; L0 full + L1 h1-terms ----
        short8 ah[2][2], al[2][2], a1h[2][2], a1l[2][2];
#pragma unroll
        for (int kc = 0; kc < 2; ++kc)
#pragma unroll
            for (int mt = 0; mt < 2; ++mt) {
                const int ro = (mt * 16 + col) * HSTR + kc * 32 + q * 8;
                ah[kc][mt]  = *(const short8*)(Hhi + B0p + ro);
                al[kc][mt]  = *(const short8*)(Hlo + B0p + ro);
                a1h[kc][mt] = *(const short8*)(Hhi + B1p + ro);
                a1l[kc][mt] = *(const short8*)(Hlo + B1p + ro);
            }
        f32x4 pre0[2][2], pre1[2][2];
#pragma unroll
        for (int g2 = 0; g2 < 2; ++g2)
#pragma unroll
            for (int mt = 0; mt < 2; ++mt) {
                pre0[g2][mt] = (f32x4){biasM0[g2], biasM0[g2], biasM0[g2], biasM0[g2]};
                pre1[g2][mt] = (f32x4){biasM1[g2], biasM1[g2], biasM1[g2], biasM1[g2]};
            }
        // L0: 6 terms x 4 chains
#pragma unroll
        for (int g2 = 0; g2 < 2; ++g2)
#pragma unroll
            for (int mt = 0; mt < 2; ++mt) pre0[g2][mt] = MFMA16(ah[0][mt], Whi[0][g2][0], pre0[g2][mt]);
#pragma unroll
        for (int g2 = 0; g2 < 2; ++g2)
#pragma unroll
            for (int mt = 0; mt < 2; ++mt) pre0[g2][mt] = MFMA16(ah[1][mt], Whi[0][g2][1], pre0[g2][mt]);
#pragma unroll
        for (int g2 = 0; g2 < 2; ++g2)
#pragma unroll
            for (int mt = 0; mt < 2; ++mt) pre0[g2][mt] = MFMA16(al[0][mt], Whi[0][g2][0], pre0[g2][mt]);
#pragma unroll
        for (int g2 = 0; g2 < 2; ++g2)
#pragma unroll
            for (int mt = 0; mt < 2; ++mt) pre0[g2][mt] = MFMA16(al[1][mt], Whi[0][g2][1], pre0[g2][mt]);
#pragma unroll
        for (int g2 = 0; g2 < 2; ++g2)
#pragma unroll
            for (int mt = 0; mt < 2; ++mt) pre0[g2][mt] = MFMA16(ah[0][mt], Wlo[0][g2][0], pre0[g2][mt]);
#pragma unroll
        for (int g2 = 0; g2 < 2; ++g2)
#pragma unroll
            for (int mt = 0; mt < 2; ++mt) pre0[g2][mt] = MFMA16(ah[1][mt], Wlo[0][g2][1], pre0[g2][mt]);
        // L1 h1-old terms: 6 x 4 chains
#pragma unroll
        for (int g2 = 0; g2 < 2; ++g2)
#pragma unroll
            for (int mt = 0; mt < 2; ++mt) pre1[g2][mt] = MFMA16(a1h[0][mt], Whi[2][g2][0], pre1[g2][mt]);
#pragma unroll
        for (int g2 = 0; g2 < 2; ++g2)
#pragma unroll
            for (int mt = 0; mt < 2; ++mt) pre1[g2][mt] = MFMA16(a1h[1][mt], Whi[2][g2][1], pre1[g2][mt]);
#pragma unroll
        for (int g2 = 0; g2 < 2; ++g2)
#pragma unroll
            for (int mt = 0; mt < 2; ++mt) pre1[g2][mt] = MFMA16(a1l[0][mt], Whi[2][g2][0], pre1[g2][mt]);
#pragma unroll
        for (int g2 = 0; g2 < 2; ++g2)
#pragma unroll
            for (int mt = 0; mt < 2; ++mt) pre1[g2][mt] = MFMA16(a1l[1][mt], Whi[2][g2][1], pre1[g2][mt]);
#pragma unroll
        for (int g2 = 0; g2 < 2; ++g2)
#pragma unroll
            for (int mt = 0; mt < 2; ++mt) pre1[g2][mt] = MFMA16(a1h[0][mt], Wlo[2][g2][0], pre1[g2][mt]);
#pragma unroll
        for (int g2 = 0; g2 < 2; ++g2)
#pragma unroll
            for (int mt = 0; mt < 2; ++mt) pre1[g2][mt] = MFMA16(a1h[1][mt], Wlo[2][g2][1], pre1[g2][mt]);
        // publish L0 preacts
#pragma unroll
        for (int g2 = 0; g2 < 2; ++g2)
#pragma unroll
            for (int mt = 0; mt < 2; ++mt)
#pragma unroll
                for (int r = 0; r < 4; ++r)
                    PRE[(2 * P + g2) * PG + (mt * 16 + q * 4 + r) * PSTR + U * 16 + col] = pre0[g2][mt][r];
        __syncthreads();   // A: PRE(L0) ready

        // ---- epilogue 0 ----
        {
            float pg[4][4];
#pragma unroll
            for (int g = 0; g < 4; ++g)
#pragma unroll
                for (int r = 0; r < 4; ++r)
                    pg[g][r] = PRE[g * PG + (me + r) * PSTR + uu];
#pragma unroll
            for (int r = 0; r < 4; ++r) {
                const float xw = xv[r];
                const float ig = sigm (pg[0][r] + xw * wih0gE[0]);
                const float fg = sigm (pg[1][r] + xw * wih0gE[1]);
                const float gt = tanh_(pg[2][r] + xw * wih0gE[2]);
                const float og = sigm (pg[3][r] + xw * wih0gE[3]);
                const float c  = fg * c0[r] + ig * gt;
                c0[r] = c;
                const float h  = og * tanh_(c);
                const short hb = f2b(h);
                const int  wi  = B0n + (me + r) * HSTR + uu;
                Hhi[wi] = hb;
                Hlo[wi] = f2b(h - b2f(hb));
            }
        }
        __syncthreads();   // B: h0(new) ready, PRE free

        // ---- phase 2: L1 h0-terms ----
        short8 bh[2][2], bl[2][2];
#pragma unroll
        for (int kc = 0; kc < 2; ++kc)
#pragma unroll
            for (int mt = 0; mt < 2; ++mt) {
                const int ro = (mt * 16 + col) * HSTR + kc * 32 + q * 8;
                bh[kc][mt] = *(const short8*)(Hhi + B0n + ro);
                bl[kc][mt] = *(const short8*)(Hlo + B0n + ro);
            }
#pragma unroll
        for (int g2 = 0; g2 < 2; ++g2)
#pragma unroll
            for (int mt = 0; mt < 2; ++mt) pre1[g2][mt] = MFMA16(bh[0][mt], Whi[1][g2][0], pre1[g2][mt]);
#pragma unroll
        for (int g2 = 0; g2 < 2; ++g2)
#pragma unroll
            for (int mt = 0; mt < 2; ++mt) pre1[g2][mt] = MFMA16(bh[1][mt], Whi[1][g2][1], pre1[g2][mt]);
#pragma unroll
        for (int g2 = 0; g2 < 2; ++g2)
#pragma unroll
            for (int mt = 0; mt < 2; ++mt) pre1[g2][mt] = MFMA16(bl[0][mt], Whi[1][g2][0], pre1[g2][mt]);
#pragma unroll
        for (int g2 = 0; g2 < 2; ++g2)
#pragma unroll
            for (int mt = 0; mt < 2; ++mt) pre1[g2][mt] = MFMA16(bl[1][mt], Whi[1][g2][1], pre1[g2][mt]);
#pragma unroll
        for (int g2 = 0; g2 < 2; ++g2)
#pragma unroll
            for (int mt = 0; mt < 2; ++mt) pre1[g2][mt] = MFMA16(bh[0][mt], Wlo[1][g2][0], pre1[g2][mt]);
#pragma unroll
        for (int g2 = 0; g2 < 2; ++g2)
#pragma unroll
            for (int mt = 0; mt < 2; ++mt) pre1[g2][mt] = MFMA16(bh[1][mt], Wlo[1][g2][1], pre1[g2][mt]);
#pragma unroll
        for (int g2 = 0; g2 < 2; ++g2)
#pragma unroll
            for (int mt = 0; mt < 2; ++mt)
#pragma unroll
                for (int r = 0; r < 4; ++r)
                    PRE[(2 * P + g2) * PG + (mt * 16 + q * 4 + r) * PSTR + U * 16 + col] = pre1[g2][mt][r];
        __syncthreads();   // C: PRE(L1) ready

        // ---- epilogue 1 ----
        {
            float pg[4][4];
#pragma unroll
            for (int g = 0; g < 4; ++g)
#pragma unroll
                for (int r = 0; r < 4; ++r)
                    pg[g][r] = PRE[g * PG + (me + r) * PSTR + uu];
#pragma unroll
            for (int r = 0; r < 4; ++r) {
                const float ig = sigm (pg[0][r]);
                const float fg = sigm (pg[1][r]);
                const float gt = tanh_(pg[2][r]);
                const float og = sigm (pg[3][r]);
                const float c  = fg * c1[r] + ig * gt;
                c1[r] = c;
                const float h  = og * tanh_(c);
                const short hb = f2b(h);
                const int  wi  = B1n + (me + r) * HSTR + uu;
                Hhi[wi] = hb;
                Hlo[wi] = f2b(h - b2f(hb));
            }
        }
        __syncthreads();   // D: h1(new) ready
    }

    // ================= decoder =================
#pragma unroll
    for (int g2 = 0; g2 < 2; ++g2) {
        const int j = (2 * P + g2) * 64 + U * 16 + col;
#pragma unroll
        for (int kc = 0; kc < 2; ++kc)
            split8(Wchh + j * 64 + kc * 32 + q * 8, Whi[0][g2][kc], Wlo[0][g2][kc]);
    }
    if (tid < 32) ybufF[tid] = xbF[(Lv - 1) * Sv + tid];
    __syncthreads();

    const float boutF = bout[0];
    float* outp = out + b * HZv * Sv + s0;

    for (int t = 0; t < HZv; ++t) {
        const int p = t & 1, np = p ^ 1;
        const int B1p = (2 + p) * HBUF, B1n = (2 + np) * HBUF;

        short8 ah[2][2], al[2][2];
#pragma unroll
        for (int kc = 0; kc < 2; ++kc)
#pragma unroll
            for (int mt = 0; mt < 2; ++mt) {
                const int ro = (mt * 16 + col) * HSTR + kc * 32 + q * 8;
                ah[kc][mt] = *(const short8*)(Hhi + B1p + ro);
                al[kc][mt] = *(const short8*)(Hlo + B1p + ro);
            }
        f32x4 prc[2][2];
#pragma unroll
        for (int g2 = 0; g2 < 2; ++g2)
#pragma unroll
            for (int mt = 0; mt < 2; ++mt)
                prc[g2][mt] = (f32x4){biasMc[g2], biasMc[g2], biasMc[g2], biasMc[g2]};
#pragma unroll
        for (int g2 = 0; g2 < 2; ++g2)
#pragma unroll
            for (int mt = 0; mt < 2; ++mt) prc[g2][mt] = MFMA16(ah[0][mt], Whi[0][g2][0], prc[g2][mt]);
#pragma unroll
        for (int g2 = 0; g2 < 2; ++g2)
#pragma unroll
            for (int mt = 0; mt < 2; ++mt) prc[g2][mt] = MFMA16(ah[1][mt], Whi[0][g2][1], prc[g2][mt]);
#pragma unroll
        for (int g2 = 0; g2 < 2; ++g2)
#pragma unroll
            for (int mt = 0; mt < 2; ++mt) prc[g2][mt] = MFMA16(al[0][mt], Whi[0][g2][0], prc[g2][mt]);
#pragma unroll
        for (int g2 = 0; g2 < 2; ++g2)
#pragma unroll
            for (int mt = 0; mt < 2; ++mt) prc[g2][mt] = MFMA16(al[1][mt], Whi[0][g2][1], prc[g2][mt]);
#pragma unroll
        for (int g2 = 0; g2 < 2; ++g2)
#pragma unroll
            for (int mt = 0; mt < 2; ++mt) prc[g2][mt] = MFMA16(ah[0][mt], Wlo[0][g2][0], prc[g2][mt]);
#pragma unroll
        for (int g2 = 0; g2 < 2; ++g2)
#pragma unroll
            for (int mt = 0; mt < 2; ++mt) prc[g2][mt] = MFMA16(ah[1][mt], Wlo[0][g2][1], prc[g2][mt]);
#pragma unroll
        for (int g2 = 0; g2 < 2; ++g2)
#pragma unroll
            for (int mt = 0; mt < 2; ++mt)
#pragma unroll
                for (int r = 0; r < 4; ++r)
                    PRE[(2 * P + g2) * PG + (mt * 16 + q * 4 + r) * PSTR + U * 16 + col] = prc[g2][mt][r];
        __syncthreads();   // A

        {
            float pg[4][4];
#pragma unroll
            for (int g = 0; g < 4; ++g)
#pragma unroll
                for (int r = 0; r < 4; ++r)
                    pg[g][r] = PRE[g * PG + (me + r) * PSTR + uu];
#pragma unroll
            for (int r = 0; r < 4; ++r) {
                const float xw = ybufF[me + r];
                const float ig = sigm (pg[0][r] + xw * wcihgE[0]);
                const float fg = sigm (pg[1][r] + xw * wcihgE[1]);
                const float gt = tanh_(pg[2][r] + xw * wcihgE[2]);
                const float og = sigm (pg[3][r] + xw * wcihgE[3]);
                const float c  = fg * c1[r] + ig * gt;
                c1[r] = c;
                const float h  = og * tanh_(c);
                const short hb = f2b(h);
                const int  wi  = B1n + (me + r) * HSTR + uu;
                Hhi[wi] = hb;
                Hlo[wi] = f2b(h - b2f(hb));
            }
        }
        __syncthreads();   // B: h(new) ready

        if (tid < 32) {    // y = h @ W_out^T + b_out (exact f32 from hi+lo)
            const int m = tid;
            float s = boutF;
#pragma unroll
            for (int k = 0; k < 64; ++k)
                s += (b2f(Hhi[B1n + m * HSTR + k]) + b2f(Hlo[B1n + m * HSTR + k])) * woutF[k];
            outp[t * Sv + m] = s;
            ybufF[m] = s;
        }
        __syncthreads();   // C: ybufF ready for next step
    }
}

extern "C" void kernel_launch(void* const* d_in, const int* in_sizes, int n_in,
                              void* d_out, int out_size, void* d_ws, size_t ws_size,
                              hipStream_t stream)
{
    const float* x_seq = (const float*)d_in[0];
    const float* Wih0  = (const float*)d_in[1];
    const float* Whh0  = (const float*)d_in[2];
    const float* bih0  = (const float*)d_in[3];
    const float* bhh0  = (const float*)d_in[4];
    const float* Wih1  = (const float*)d_in[5];
    const float* Whh1  = (const float*)d_in[6];
    const float* bih1  = (const float*)d_in[7];
    const float* bhh1  = (const float*)d_in[8];
    const float* Wcih  = (const float*)d_in[9];
    const float* Wchh  = (const float*)d_in[10];
    const float* bcih  = (const float*)d_in[11];
    const float* bchh  = (const float*)d_in[12];
    const float* Wout  = (const float*)d_in[13];
    const float* bout  = (const float*)d_in[14];
    float* out = (float*)d_out;

    hipLaunchKernelGGL(sitewise_lstm, dim3(Bv * (Sv / 32)), dim3(512), 0, stream,
                       x_seq, Wih0, Whh0, bih0, bhh0, Wih1, Whh1, bih1, bhh1,
                       Wcih, Wchh, bcih, bchh, Wout, bout, out);
}

// Round 10
// 1339.910 us; speedup vs baseline: 1.5709x; 1.5709x over previous
//
#include <hip/hip_runtime.h>

typedef __attribute__((ext_vector_type(8))) short short8;
typedef __attribute__((ext_vector_type(4))) float f32x4;

#define MFMA16(a, b, c) __builtin_amdgcn_mfma_f32_16x16x32_bf16((a), (b), (c), 0, 0, 0)

constexpr int Bv  = 32;    // batch
constexpr int Lv  = 168;   // encoder length
constexpr int Sv  = 512;   // sites
constexpr int HZv = 24;    // horizon
constexpr int HSTR = 88;   // h-row stride (shorts): 176 B/row, 16B-aligned b128
constexpr int HBUF = 32 * HSTR;
constexpr int PSTR = 66;   // PRE row stride (f32)
constexpr int PG   = 32 * PSTR;

__device__ __forceinline__ float b2f(short s) {
    unsigned u = ((unsigned)(unsigned short)s) << 16;
    return __builtin_bit_cast(float, u);
}
__device__ __forceinline__ short f2b(float f) {
    unsigned u = __builtin_bit_cast(unsigned, f);
    unsigned r = (u + 0x7FFFu + ((u >> 16) & 1u)) >> 16;   // RNE
    return (short)(unsigned short)r;
}
__device__ __forceinline__ float sigm(float x) {
    x = fmaxf(x, -85.0f);
    float e = __builtin_amdgcn_exp2f(-1.44269504088896f * x);
    return __builtin_amdgcn_rcpf(1.0f + e);
}
__device__ __forceinline__ float tanh_(float x) {
    x = fminf(x, 43.0f);
    float e = __builtin_amdgcn_exp2f(2.88539008177793f * x); // exp(2x)
    return 1.0f - 2.0f * __builtin_amdgcn_rcpf(e + 1.0f);
}
__device__ __forceinline__ void split8(const float* __restrict__ p, short8& hi, short8& lo) {
#pragma unroll
    for (int j = 0; j < 8; ++j) {
        float x = p[j];
        short h = f2b(x);
        hi[j] = h;
        lo[j] = f2b(x - b2f(h));
    }
}

// 512-thread block (8 waves), M=32 seqs. Wave w: unit-slice U=w&3, gate-pair P=w>>2.
// LDS 77.4 KB -> 2 blocks/CU by LDS. VGPR: compiler chooses ~124 (r8 measured) ->
// 4 waves/EU by registers too. NO second launch_bounds arg: r9's (512,4) forced
// VGPR=64 and catastrophic spills (FETCH 6.9 GB).
__global__ __launch_bounds__(512)
void sitewise_lstm(const float* __restrict__ x_seq,
                   const float* __restrict__ Wih0, const float* __restrict__ Whh0,
                   const float* __restrict__ bih0, const float* __restrict__ bhh0,
                   const float* __restrict__ Wih1, const float* __restrict__ Whh1,
                   const float* __restrict__ bih1, const float* __restrict__ bhh1,
                   const float* __restrict__ Wcih, const float* __restrict__ Wchh,
                   const float* __restrict__ bcih, const float* __restrict__ bchh,
                   const float* __restrict__ Wout, const float* __restrict__ bout,
                   float* __restrict__ out)
{
    __shared__ __align__(16) short Hhi[4 * HBUF];   // 22.5 KB
    __shared__ __align__(16) short Hlo[4 * HBUF];   // 22.5 KB
    __shared__ __align__(16) float PRE[4 * PG];     // 33.8 KB preactivation exchange
    __shared__ float woutF[64];
    __shared__ float ybufF[32];

    const int tid  = threadIdx.x;
    const int wv   = tid >> 6;
    const int lane = tid & 63;
    const int q    = lane >> 4;
    const int col  = lane & 15;
    const int U    = wv & 3;      // unit-slice: u in [16U, 16U+16)
    const int P    = wv >> 2;     // MFMA: gates {2P, 2P+1}; epilogue: m-half [16P, 16P+16)
    const int bid  = blockIdx.x;
    const int b    = bid >> 4;
    const int s0   = (bid & 15) << 5;
    const int uu   = U * 16 + col;          // epilogue unit column
    const int me   = P * 16 + q * 4;        // epilogue m base (+r)

    for (int i = tid; i < 4 * HBUF / 2; i += 512) { ((int*)Hhi)[i] = 0; ((int*)Hlo)[i] = 0; }
    if (tid < 64) woutF[tid] = Wout[tid];

    const float* xbF = x_seq + b * Lv * Sv + s0;

    // ---- per-wave weights: 2 gate-tiles per matrix, hi+lo in registers ----
    short8 Whi[3][2][2], Wlo[3][2][2];   // [Whh0|Wih1|Whh1][g2][kc]; slot0 -> Wchh in decoder
    float biasM0[2], biasM1[2], biasMc[2];
    float wih0gE[4], wcihgE[4];
#pragma unroll
    for (int g2 = 0; g2 < 2; ++g2) {
        const int g = 2 * P + g2;
        const int j = g * 64 + U * 16 + col;
        biasM0[g2] = bih0[j] + bhh0[j];
        biasM1[g2] = bih1[j] + bhh1[j];
        biasMc[g2] = bcih[j] + bchh[j];
#pragma unroll
        for (int kc = 0; kc < 2; ++kc) {
            const int off = j * 64 + kc * 32 + q * 8;
            split8(Whh0 + off, Whi[0][g2][kc], Wlo[0][g2][kc]);
            split8(Wih1 + off, Whi[1][g2][kc], Wlo[1][g2][kc]);
            split8(Whh1 + off, Whi[2][g2][kc], Wlo[2][g2][kc]);
        }
    }
#pragma unroll
    for (int g = 0; g < 4; ++g) {
        wih0gE[g] = Wih0[g * 64 + uu];
        wcihgE[g] = Wcih[g * 64 + uu];
    }

    float c0[4], c1[4];
#pragma unroll
    for (int i = 0; i < 4; ++i) { c0[i] = 0.f; c1[i] = 0.f; }

    __syncthreads();

    // ================= encoder =================
    for (int t = 0; t < Lv; ++t) {
        const int p = t & 1, np = p ^ 1;
        const int B0p = p * HBUF, B0n = np * HBUF;
        const int B1p = (2 + p) * HBUF, B1n = (2 + np) * HBUF;

        // issue x load early (consumed in epilogue 0 -> hidden under MFMA phase)
        const f32x4 xv = *(const f32x4*)(xbF + t * Sv + me);

        // ---- phase 1: old-state fragments; L0 full + L1 h1-terms ----
        short8 ah[2][2], al[2][2], a1h[2][2], a1l[2][2];
#pragma unroll
        for (int kc = 0; kc < 2; ++kc)
#pragma unroll
            for (int mt = 0; mt < 2; ++mt) {
                const int ro = (mt * 16 + col) * HSTR + kc * 32 + q * 8;
                ah[kc][mt]  = *(const short8*)(Hhi + B0p + ro);
                al[kc][mt]  = *(const short8*)(Hlo + B0p + ro);
                a1h[kc][mt] = *(const short8*)(Hhi + B1p + ro);
                a1l[kc][mt] = *(const short8*)(Hlo + B1p + ro);
            }
        f32x4 pre0[2][2], pre1[2][2];
#pragma unroll
        for (int g2 = 0; g2 < 2; ++g2)
#pragma unroll
            for (int mt = 0; mt < 2; ++mt) {
                pre0[g2][mt] = (f32x4){biasM0[g2], biasM0[g2], biasM0[g2], biasM0[g2]};
                pre1[g2][mt] = (f32x4){biasM1[g2], biasM1[g2], biasM1[g2], biasM1[g2]};
            }
        // L0: 6 terms x 4 chains
#pragma unroll
        for (int g2 = 0; g2 < 2; ++g2)
#pragma unroll
            for (int mt = 0; mt < 2; ++mt) pre0[g2][mt] = MFMA16(ah[0][mt], Whi[0][g2][0], pre0[g2][mt]);
#pragma unroll
        for (int g2 = 0; g2 < 2; ++g2)
#pragma unroll
            for (int mt = 0; mt < 2; ++mt) pre0[g2][mt] = MFMA16(ah[1][mt], Whi[0][g2][1], pre0[g2][mt]);
#pragma unroll
        for (int g2 = 0; g2 < 2; ++g2)
#pragma unroll
            for (int mt = 0; mt < 2; ++mt) pre0[g2][mt] = MFMA16(al[0][mt], Whi[0][g2][0], pre0[g2][mt]);
#pragma unroll
        for (int g2 = 0; g2 < 2; ++g2)
#pragma unroll
            for (int mt = 0; mt < 2; ++mt) pre0[g2][mt] = MFMA16(al[1][mt], Whi[0][g2][1], pre0[g2][mt]);
#pragma unroll
        for (int g2 = 0; g2 < 2; ++g2)
#pragma unroll
            for (int mt = 0; mt < 2; ++mt) pre0[g2][mt] = MFMA16(ah[0][mt], Wlo[0][g2][0], pre0[g2][mt]);
#pragma unroll
        for (int g2 = 0; g2 < 2; ++g2)
#pragma unroll
            for (int mt = 0; mt < 2; ++mt) pre0[g2][mt] = MFMA16(ah[1][mt], Wlo[0][g2][1], pre0[g2][mt]);
        // L1 h1-old terms: 6 x 4 chains
#pragma unroll
        for (int g2 = 0; g2 < 2; ++g2)
#pragma unroll
            for (int mt = 0; mt < 2; ++mt) pre1[g2][mt] = MFMA16(a1h[0][mt], Whi[2][g2][0], pre1[g2][mt]);
#pragma unroll
        for (int g2 = 0; g2 < 2; ++g2)
#pragma unroll
            for (int mt = 0; mt < 2; ++mt) pre1[g2][mt] = MFMA16(a1h[1][mt], Whi[2][g2][1], pre1[g2][mt]);
#pragma unroll
        for (int g2 = 0; g2 < 2; ++g2)
#pragma unroll
            for (int mt = 0; mt < 2; ++mt) pre1[g2][mt] = MFMA16(a1l[0][mt], Whi[2][g2][0], pre1[g2][mt]);
#pragma unroll
        for (int g2 = 0; g2 < 2; ++g2)
#pragma unroll
            for (int mt = 0; mt < 2; ++mt) pre1[g2][mt] = MFMA16(a1l[1][mt], Whi[2][g2][1], pre1[g2][mt]);
#pragma unroll
        for (int g2 = 0; g2 < 2; ++g2)
#pragma unroll
            for (int mt = 0; mt < 2; ++mt) pre1[g2][mt] = MFMA16(a1h[0][mt], Wlo[2][g2][0], pre1[g2][mt]);
#pragma unroll
        for (int g2 = 0; g2 < 2; ++g2)
#pragma unroll
            for (int mt = 0; mt < 2; ++mt) pre1[g2][mt] = MFMA16(a1h[1][mt], Wlo[2][g2][1], pre1[g2][mt]);
        // publish L0 preacts
#pragma unroll
        for (int g2 = 0; g2 < 2; ++g2)
#pragma unroll
            for (int mt = 0; mt < 2; ++mt)
#pragma unroll
                for (int r = 0; r < 4; ++r)
                    PRE[(2 * P + g2) * PG + (mt * 16 + q * 4 + r) * PSTR + U * 16 + col] = pre0[g2][mt][r];
        __syncthreads();   // A: PRE(L0) ready

        // ---- epilogue 0 ----
        {
            float pg[4][4];
#pragma unroll
            for (int g = 0; g < 4; ++g)
#pragma unroll
                for (int r = 0; r < 4; ++r)
                    pg[g][r] = PRE[g * PG + (me + r) * PSTR + uu];
#pragma unroll
            for (int r = 0; r < 4; ++r) {
                const float xw = xv[r];
                const float ig = sigm (pg[0][r] + xw * wih0gE[0]);
                const float fg = sigm (pg[1][r] + xw * wih0gE[1]);
                const float gt = tanh_(pg[2][r] + xw * wih0gE[2]);
                const float og = sigm (pg[3][r] + xw * wih0gE[3]);
                const float c  = fg * c0[r] + ig * gt;
                c0[r] = c;
                const float h  = og * tanh_(c);
                const short hb = f2b(h);
                const int  wi  = B0n + (me + r) * HSTR + uu;
                Hhi[wi] = hb;
                Hlo[wi] = f2b(h - b2f(hb));
            }
        }
        __syncthreads();   // B: h0(new) ready, PRE free

        // ---- phase 2: L1 h0-terms ----
        short8 bh[2][2], bl[2][2];
#pragma unroll
        for (int kc = 0; kc < 2; ++kc)
#pragma unroll
            for (int mt = 0; mt < 2; ++mt) {
                const int ro = (mt * 16 + col) * HSTR + kc * 32 + q * 8;
                bh[kc][mt] = *(const short8*)(Hhi + B0n + ro);
                bl[kc][mt] = *(const short8*)(Hlo + B0n + ro);
            }
#pragma unroll
        for (int g2 = 0; g2 < 2; ++g2)
#pragma unroll
            for (int mt = 0; mt < 2; ++mt) pre1[g2][mt] = MFMA16(bh[0][mt], Whi[1][g2][0], pre1[g2][mt]);
#pragma unroll
        for (int g2 = 0; g2 < 2; ++g2)
#pragma unroll
            for (int mt = 0; mt < 2; ++mt) pre1[g2][mt] = MFMA16(bh[1][mt], Whi[1][g2][1], pre1[g2][mt]);
#pragma unroll
        for (int g2 = 0; g2 < 2; ++g2)
#pragma unroll
            for (int mt = 0; mt < 2; ++mt) pre1[g2][mt] = MFMA16(bl[0][mt], Whi[1][g2][0], pre1[g2][mt]);
#pragma unroll
        for (int g2 = 0; g2 < 2; ++g2)
#pragma unroll
            for (int mt = 0; mt < 2; ++mt) pre1[g2][mt] = MFMA16(bl[1][mt], Whi[1][g2][1], pre1[g2][mt]);
#pragma unroll
        for (int g2 = 0; g2 < 2; ++g2)
#pragma unroll
            for (int mt = 0; mt < 2; ++mt) pre1[g2][mt] = MFMA16(bh[0][mt], Wlo[1][g2][0], pre1[g2][mt]);
#pragma unroll
        for (int g2 = 0; g2 < 2; ++g2)
#pragma unroll
            for (int mt = 0; mt < 2; ++mt) pre1[g2][mt] = MFMA16(bh[1][mt], Wlo[1][g2][1], pre1[g2][mt]);
#pragma unroll
        for (int g2 = 0; g2 < 2; ++g2)
#pragma unroll
            for (int mt = 0; mt < 2; ++mt)
#pragma unroll
                for (int r = 0; r < 4; ++r)
                    PRE[(2 * P + g2) * PG + (mt * 16 + q * 4 + r) * PSTR + U * 16 + col] = pre1[g2][mt][r];
        __syncthreads();   // C: PRE(L1) ready

        // ---- epilogue 1 ----
        {
            float pg[4][4];
#pragma unroll
            for (int g = 0; g < 4; ++g)
#pragma unroll
                for (int r = 0; r < 4; ++r)
                    pg[g][r] = PRE[g * PG + (me + r) * PSTR + uu];
#pragma unroll
            for (int r = 0; r < 4; ++r) {
                const float ig = sigm (pg[0][r]);
                const float fg = sigm (pg[1][r]);
                const float gt = tanh_(pg[2][r]);
                const float og = sigm (pg[3][r]);
                const float c  = fg * c1[r] + ig * gt;
                c1[r] = c;
                const float h  = og * tanh_(c);
                const short hb = f2b(h);
                const int  wi  = B1n + (me + r) * HSTR + uu;
                Hhi[wi] = hb;
                Hlo[wi] = f2b(h - b2f(hb));
            }
        }
        __syncthreads();   // D: h1(new) ready
    }

    // ================= decoder =================
#pragma unroll
    for (int g2 = 0; g2 < 2; ++g2) {
        const int j = (2 * P + g2) * 64 + U * 16 + col;
#pragma unroll
        for (int kc = 0; kc < 2; ++kc)
            split8(Wchh + j * 64 + kc * 32 + q * 8, Whi[0][g2][kc], Wlo[0][g2][kc]);
    }
    if (tid < 32) ybufF[tid] = xbF[(Lv - 1) * Sv + tid];
    __syncthreads();

    const float boutF = bout[0];
    float* outp = out + b * HZv * Sv + s0;

    for (int t = 0; t < HZv; ++t) {
        const int p = t & 1, np = p ^ 1;
        const int B1p = (2 + p) * HBUF, B1n = (2 + np) * HBUF;

        short8 ah[2][2], al[2][2];
#pragma unroll
        for (int kc = 0; kc < 2; ++kc)
#pragma unroll
            for (int mt = 0; mt < 2; ++mt) {
                const int ro = (mt * 16 + col) * HSTR + kc * 32 + q * 8;
                ah[kc][mt] = *(const short8*)(Hhi + B1p + ro);
                al[kc][mt] = *(const short8*)(Hlo + B1p + ro);
            }
        f32x4 prc[2][2];
#pragma unroll
        for (int g2 = 0; g2 < 2; ++g2)
#pragma unroll
            for (int mt = 0; mt < 2; ++mt)
                prc[g2][mt] = (f32x4){biasMc[g2], biasMc[g2], biasMc[g2], biasMc[g2]};
#pragma unroll
        for (int g2 = 0; g2 < 2; ++g2)
#pragma unroll
            for (int mt = 0; mt < 2; ++mt) prc[g2][mt] = MFMA16(ah[0][mt], Whi[0][g2][0], prc[g2][mt]);
#pragma unroll
        for (int g2 = 0; g2 < 2; ++g2)
#pragma unroll
            for (int mt = 0; mt < 2; ++mt) prc[g2][mt] = MFMA16(ah[1][mt], Whi[0][g2][1], prc[g2][mt]);
#pragma unroll
        for (int g2 = 0; g2 < 2; ++g2)
#pragma unroll
            for (int mt = 0; mt < 2; ++mt) prc[g2][mt] = MFMA16(al[0][mt], Whi[0][g2][0], prc[g2][mt]);
#pragma unroll
        for (int g2 = 0; g2 < 2; ++g2)
#pragma unroll
            for (int mt = 0; mt < 2; ++mt) prc[g2][mt] = MFMA16(al[1][mt], Whi[0][g2][1], prc[g2][mt]);
#pragma unroll
        for (int g2 = 0; g2 < 2; ++g2)
#pragma unroll
            for (int mt = 0; mt < 2; ++mt) prc[g2][mt] = MFMA16(ah[0][mt], Wlo[0][g2][0], prc[g2][mt]);
#pragma unroll
        for (int g2 = 0; g2 < 2; ++g2)
#pragma unroll
            for (int mt = 0; mt < 2; ++mt) prc[g2][mt] = MFMA16(ah[1][mt], Wlo[0][g2][1], prc[g2][mt]);
#pragma unroll
        for (int g2 = 0; g2 < 2; ++g2)
#pragma unroll
            for (int mt = 0; mt < 2; ++mt)
#pragma unroll
                for (int r = 0; r < 4; ++r)
                    PRE[(2 * P + g2) * PG + (mt * 16 + q * 4 + r) * PSTR + U * 16 + col] = prc[g2][mt][r];
        __syncthreads();   // A

        {
            float pg[4][4];
#pragma unroll
            for (int g = 0; g < 4; ++g)
#pragma unroll
                for (int r = 0; r < 4; ++r)
                    pg[g][r] = PRE[g * PG + (me + r) * PSTR + uu];
#pragma unroll
            for (int r = 0; r < 4; ++r) {
                const float xw = ybufF[me + r];
                const float ig = sigm (pg[0][r] + xw * wcihgE[0]);
                const float fg = sigm (pg[1][r] + xw * wcihgE[1]);
                const float gt = tanh_(pg[2][r] + xw * wcihgE[2]);
                const float og = sigm (pg[3][r] + xw * wcihgE[3]);
                const float c  = fg * c1[r] + ig * gt;
                c1[r] = c;
                const float h  = og * tanh_(c);
                const short hb = f2b(h);
                const int  wi  = B1n + (me + r) * HSTR + uu;
                Hhi[wi] = hb;
                Hlo[wi] = f2b(h - b2f(hb));
            }
        }
        __syncthreads();   // B: h(new) ready

        if (tid < 32) {    // y = h @ W_out^T + b_out (exact f32 from hi+lo)
            const int m = tid;
            float s = boutF;
#pragma unroll
            for (int k = 0; k < 64; ++k)
                s += (b2f(Hhi[B1n + m * HSTR + k]) + b2f(Hlo[B1n + m * HSTR + k])) * woutF[k];
            outp[t * Sv + m] = s;
            ybufF[m] = s;
        }
        __syncthreads();   // C: ybufF ready for next step
    }
}

extern "C" void kernel_launch(void* const* d_in, const int* in_sizes, int n_in,
                              void* d_out, int out_size, void* d_ws, size_t ws_size,
                              hipStream_t stream)
{
    const float* x_seq = (const float*)d_in[0];
    const float* Wih0  = (const float*)d_in[1];
    const float* Whh0  = (const float*)d_in[2];
    const float* bih0  = (const float*)d_in[3];
    const float* bhh0  = (const float*)d_in[4];
    const float* Wih1  = (const float*)d_in[5];
    const float* Whh1  = (const float*)d_in[6];
    const float* bih1  = (const float*)d_in[7];
    const float* bhh1  = (const float*)d_in[8];
    const float* Wcih  = (const float*)d_in[9];
    const float* Wchh  = (const float*)d_in[10];
    const float* bcih  = (const float*)d_in[11];
    const float* bchh  = (const float*)d_in[12];
    const float* Wout  = (const float*)d_in[13];
    const float* bout  = (const float*)d_in[14];
    float* out = (float*)d_out;

    hipLaunchKernelGGL(sitewise_lstm, dim3(Bv * (Sv / 32)), dim3(512), 0, stream,
                       x_seq, Wih0, Whh0, bih0, bhh0, Wih1, Whh1, bih1, bhh1,
                       Wcih, Wchh, bcih, bchh, Wout, bout, out);
}

// Round 11
// 1235.088 us; speedup vs baseline: 1.7043x; 1.0849x over previous
//
#include <hip/hip_runtime.h>

typedef __attribute__((ext_vector_type(8))) short short8;
typedef __attribute__((ext_vector_type(4))) float f32x4;

#define MFMA16(a, b, c) __builtin_amdgcn_mfma_f32_16x16x32_bf16((a), (b), (c), 0, 0, 0)

constexpr int Bv  = 32;    // batch
constexpr int Lv  = 168;   // encoder length
constexpr int Sv  = 512;   // sites
constexpr int HZv = 24;    // horizon
constexpr int HSTR = 88;   // h-row stride (shorts): 176 B/row, 16B-aligned b128
constexpr int HBUF = 32 * HSTR;
constexpr int PSTR = 66;   // PRE row stride (f32)
constexpr int PG   = 32 * PSTR;

__device__ __forceinline__ float b2f(short s) {
    unsigned u = ((unsigned)(unsigned short)s) << 16;
    return __builtin_bit_cast(float, u);
}
__device__ __forceinline__ short f2b(float f) {
    unsigned u = __builtin_bit_cast(unsigned, f);
    unsigned r = (u + 0x7FFFu + ((u >> 16) & 1u)) >> 16;   // RNE
    return (short)(unsigned short)r;
}
__device__ __forceinline__ float sigm(float x) {
    x = fmaxf(x, -85.0f);
    float e = __builtin_amdgcn_exp2f(-1.44269504088896f * x);
    return __builtin_amdgcn_rcpf(1.0f + e);
}
__device__ __forceinline__ float tanh_(float x) {
    x = fminf(x, 43.0f);
    float e = __builtin_amdgcn_exp2f(2.88539008177793f * x); // exp(2x)
    return 1.0f - 2.0f * __builtin_amdgcn_rcpf(e + 1.0f);
}
__device__ __forceinline__ void hi8(const float* __restrict__ p, short8& hi) {
#pragma unroll
    for (int j = 0; j < 8; ++j) hi[j] = f2b(p[j]);
}

// 512-thread block (8 waves), M=32 seqs. Wave w: unit-slice U=w&3, gate-pair P=w>>2.
// W single-bf16 (RNE), h kept hi+lo -> 2 MFMA terms/matrix (was 3), 48 weight VGPRs.
// launch_bounds(512,2): r9 calibration says arg acts as blocks/CU -> 4 waves/EU ->
// 128-reg cap incl AGPR -> 2 blocks/CU co-resident (LDS 77.4 KB x2 fits 160 KB).
__global__ __launch_bounds__(512, 2)
void sitewise_lstm(const float* __restrict__ x_seq,
                   const float* __restrict__ Wih0, const float* __restrict__ Whh0,
                   const float* __restrict__ bih0, const float* __restrict__ bhh0,
                   const float* __restrict__ Wih1, const float* __restrict__ Whh1,
                   const float* __restrict__ bih1, const float* __restrict__ bhh1,
                   const float* __restrict__ Wcih, const float* __restrict__ Wchh,
                   const float* __restrict__ bcih, const float* __restrict__ bchh,
                   const float* __restrict__ Wout, const float* __restrict__ bout,
                   float* __restrict__ out)
{
    __shared__ __align__(16) short Hhi[4 * HBUF];   // 22.5 KB
    __shared__ __align__(16) short Hlo[4 * HBUF];   // 22.5 KB
    __shared__ __align__(16) float PRE[4 * PG];     // 33.8 KB preactivation exchange
    __shared__ float woutF[64];
    __shared__ float ybufF[32];

    const int tid  = threadIdx.x;
    const int wv   = tid >> 6;
    const int lane = tid & 63;
    const int q    = lane >> 4;
    const int col  = lane & 15;
    const int U    = wv & 3;      // unit-slice: u in [16U, 16U+16)
    const int P    = wv >> 2;     // MFMA: gates {2P, 2P+1}; epilogue: m-half [16P, 16P+16)
    const int bid  = blockIdx.x;
    const int b    = bid >> 4;
    const int s0   = (bid & 15) << 5;
    const int uu   = U * 16 + col;          // epilogue unit column
    const int me   = P * 16 + q * 4;        // epilogue m base (+r)

    for (int i = tid; i < 4 * HBUF / 2; i += 512) { ((int*)Hhi)[i] = 0; ((int*)Hlo)[i] = 0; }
    if (tid < 64) woutF[tid] = Wout[tid];

    const float* xbF = x_seq + b * Lv * Sv + s0;

    // ---- per-wave weights: 2 gate-tiles per matrix, single bf16 (RNE) ----
    short8 Whi[3][2][2];   // [Whh0|Wih1|Whh1][g2][kc]; slot0 -> Wchh in decoder
    float biasM0[2], biasM1[2], biasMc[2];
    float wih0gE[4], wcihgE[4];
#pragma unroll
    for (int g2 = 0; g2 < 2; ++g2) {
        const int g = 2 * P + g2;
        const int j = g * 64 + U * 16 + col;
        biasM0[g2] = bih0[j] + bhh0[j];
        biasM1[g2] = bih1[j] + bhh1[j];
        biasMc[g2] = bcih[j] + bchh[j];
#pragma unroll
        for (int kc = 0; kc < 2; ++kc) {
            const int off = j * 64 + kc * 32 + q * 8;
            hi8(Whh0 + off, Whi[0][g2][kc]);
            hi8(Wih1 + off, Whi[1][g2][kc]);
            hi8(Whh1 + off, Whi[2][g2][kc]);
        }
    }
#pragma unroll
    for (int g = 0; g < 4; ++g) {
        wih0gE[g] = Wih0[g * 64 + uu];
        wcihgE[g] = Wcih[g * 64 + uu];
    }

    float c0[4], c1[4];
#pragma unroll
    for (int i = 0; i < 4; ++i) { c0[i] = 0.f; c1[i] = 0.f; }

    __syncthreads();

    // ================= encoder =================
    for (int t = 0; t < Lv; ++t) {
        const int p = t & 1, np = p ^ 1;
        const int B0p = p * HBUF, B0n = np * HBUF;
        const int B1p = (2 + p) * HBUF, B1n = (2 + np) * HBUF;

        // issue x load early (consumed in epilogue 0 -> hidden under MFMA phase)
        const f32x4 xv = *(const f32x4*)(xbF + t * Sv + me);

        // ---- phase 1: old-state fragments; L0 full + L1 h1-terms ----
        short8 ah[2][2], al[2][2], a1h[2][2], a1l[2][2];
#pragma unroll
        for (int kc = 0; kc < 2; ++kc)
#pragma unroll
            for (int mt = 0; mt < 2; ++mt) {
                const int ro = (mt * 16 + col) * HSTR + kc * 32 + q * 8;
                ah[kc][mt]  = *(const short8*)(Hhi + B0p + ro);
                al[kc][mt]  = *(const short8*)(Hlo + B0p + ro);
                a1h[kc][mt] = *(const short8*)(Hhi + B1p + ro);
                a1l[kc][mt] = *(const short8*)(Hlo + B1p + ro);
            }
        f32x4 pre0[2][2], pre1[2][2];
#pragma unroll
        for (int g2 = 0; g2 < 2; ++g2)
#pragma unroll
            for (int mt = 0; mt < 2; ++mt) {
                pre0[g2][mt] = (f32x4){biasM0[g2], biasM0[g2], biasM0[g2], biasM0[g2]};
                pre1[g2][mt] = (f32x4){biasM1[g2], biasM1[g2], biasM1[g2], biasM1[g2]};
            }
        // L0: (h_hi + h_lo) @ Whh0 -> 4 terms x 4 chains
#pragma unroll
        for (int g2 = 0; g2 < 2; ++g2)
#pragma unroll
            for (int mt = 0; mt < 2; ++mt) pre0[g2][mt] = MFMA16(ah[0][mt], Whi[0][g2][0], pre0[g2][mt]);
#pragma unroll
        for (int g2 = 0; g2 < 2; ++g2)
#pragma unroll
            for (int mt = 0; mt < 2; ++mt) pre0[g2][mt] = MFMA16(ah[1][mt], Whi[0][g2][1], pre0[g2][mt]);
#pragma unroll
        for (int g2 = 0; g2 < 2; ++g2)
#pragma unroll
            for (int mt = 0; mt < 2; ++mt) pre0[g2][mt] = MFMA16(al[0][mt], Whi[0][g2][0], pre0[g2][mt]);
#pragma unroll
        for (int g2 = 0; g2 < 2; ++g2)
#pragma unroll
            for (int mt = 0; mt < 2; ++mt) pre0[g2][mt] = MFMA16(al[1][mt], Whi[0][g2][1], pre0[g2][mt]);
        // L1 h1-old terms: 4 x 4 chains
#pragma unroll
        for (int g2 = 0; g2 < 2; ++g2)
#pragma unroll
            for (int mt = 0; mt < 2; ++mt) pre1[g2][mt] = MFMA16(a1h[0][mt], Whi[2][g2][0], pre1[g2][mt]);
#pragma unroll
        for (int g2 = 0; g2 < 2; ++g2)
#pragma unroll
            for (int mt = 0; mt < 2; ++mt) pre1[g2][mt] = MFMA16(a1h[1][mt], Whi[2][g2][1], pre1[g2][mt]);
#pragma unroll
        for (int g2 = 0; g2 < 2; ++g2)
#pragma unroll
            for (int mt = 0; mt < 2; ++mt) pre1[g2][mt] = MFMA16(a1l[0][mt], Whi[2][g2][0], pre1[g2][mt]);
#pragma unroll
        for (int g2 = 0; g2 < 2; ++g2)
#pragma unroll
            for (int mt = 0; mt < 2; ++mt) pre1[g2][mt] = MFMA16(a1l[1][mt], Whi[2][g2][1], pre1[g2][mt]);
        // publish L0 preacts
#pragma unroll
        for (int g2 = 0; g2 < 2; ++g2)
#pragma unroll
            for (int mt = 0; mt < 2; ++mt)
#pragma unroll
                for (int r = 0; r < 4; ++r)
                    PRE[(2 * P + g2) * PG + (mt * 16 + q * 4 + r) * PSTR + U * 16 + col] = pre0[g2][mt][r];
        __syncthreads();   // A: PRE(L0) ready

        // ---- epilogue 0 ----
        {
            float pg[4][4];
#pragma unroll
            for (int g = 0; g < 4; ++g)
#pragma unroll
                for (int r = 0; r < 4; ++r)
                    pg[g][r] = PRE[g * PG + (me + r) * PSTR + uu];
#pragma unroll
            for (int r = 0; r < 4; ++r) {
                const float xw = xv[r];
                const float ig = sigm (pg[0][r] + xw * wih0gE[0]);
                const float fg = sigm (pg[1][r] + xw * wih0gE[1]);
                const float gt = tanh_(pg[2][r] + xw * wih0gE[2]);
                const float og = sigm (pg[3][r] + xw * wih0gE[3]);
                const float c  = fg * c0[r] + ig * gt;
                c0[r] = c;
                const float h  = og * tanh_(c);
                const short hb = f2b(h);
                const int  wi  = B0n + (me + r) * HSTR + uu;
                Hhi[wi] = hb;
                Hlo[wi] = f2b(h - b2f(hb));
            }
        }
        __syncthreads();   // B: h0(new) ready, PRE free

        // ---- phase 2: L1 h0-terms ----
        short8 bh[2][2], bl[2][2];
#pragma unroll
        for (int kc = 0; kc < 2; ++kc)
#pragma unroll
            for (int mt = 0; mt < 2; ++mt) {
                const int ro = (mt * 16 + col) * HSTR + kc * 32 + q * 8;
                bh[kc][mt] = *(const short8*)(Hhi + B0n + ro);
                bl[kc][mt] = *(const short8*)(Hlo + B0n + ro);
            }
#pragma unroll
        for (int g2 = 0; g2 < 2; ++g2)
#pragma unroll
            for (int mt = 0; mt < 2; ++mt) pre1[g2][mt] = MFMA16(bh[0][mt], Whi[1][g2][0], pre1[g2][mt]);
#pragma unroll
        for (int g2 = 0; g2 < 2; ++g2)
#pragma unroll
            for (int mt = 0; mt < 2; ++mt) pre1[g2][mt] = MFMA16(bh[1][mt], Whi[1][g2][1], pre1[g2][mt]);
#pragma unroll
        for (int g2 = 0; g2 < 2; ++g2)
#pragma unroll
            for (int mt = 0; mt < 2; ++mt) pre1[g2][mt] = MFMA16(bl[0][mt], Whi[1][g2][0], pre1[g2][mt]);
#pragma unroll
        for (int g2 = 0; g2 < 2; ++g2)
#pragma unroll
            for (int mt = 0; mt < 2; ++mt) pre1[g2][mt] = MFMA16(bl[1][mt], Whi[1][g2][1], pre1[g2][mt]);
#pragma unroll
        for (int g2 = 0; g2 < 2; ++g2)
#pragma unroll
            for (int mt = 0; mt < 2; ++mt)
#pragma unroll
                for (int r = 0; r < 4; ++r)
                    PRE[(2 * P + g2) * PG + (mt * 16 + q * 4 + r) * PSTR + U * 16 + col] = pre1[g2][mt][r];
        __syncthreads();   // C: PRE(L1) ready

        // ---- epilogue 1 ----
        {
            float pg[4][4];
#pragma unroll
            for (int g = 0; g < 4; ++g)
#pragma unroll
                for (int r = 0; r < 4; ++r)
                    pg[g][r] = PRE[g * PG + (me + r) * PSTR + uu];
#pragma unroll
            for (int r = 0; r < 4; ++r) {
                const float ig = sigm (pg[0][r]);
                const float fg = sigm (pg[1][r]);
                const float gt = tanh_(pg[2][r]);
                const float og = sigm (pg[3][r]);
                const float c  = fg * c1[r] + ig * gt;
                c1[r] = c;
                const float h  = og * tanh_(c);
                const short hb = f2b(h);
                const int  wi  = B1n + (me + r) * HSTR + uu;
                Hhi[wi] = hb;
                Hlo[wi] = f2b(h - b2f(hb));
            }
        }
        __syncthreads();   // D: h1(new) ready
    }

    // ================= decoder =================
#pragma unroll
    for (int g2 = 0; g2 < 2; ++g2) {
        const int j = (2 * P + g2) * 64 + U * 16 + col;
#pragma unroll
        for (int kc = 0; kc < 2; ++kc)
            hi8(Wchh + j * 64 + kc * 32 + q * 8, Whi[0][g2][kc]);
    }
    if (tid < 32) ybufF[tid] = xbF[(Lv - 1) * Sv + tid];
    __syncthreads();

    const float boutF = bout[0];
    float* outp = out + b * HZv * Sv + s0;

    for (int t = 0; t < HZv; ++t) {
        const int p = t & 1, np = p ^ 1;
        const int B1p = (2 + p) * HBUF, B1n = (2 + np) * HBUF;

        short8 ah[2][2], al[2][2];
#pragma unroll
        for (int kc = 0; kc < 2; ++kc)
#pragma unroll
            for (int mt = 0; mt < 2; ++mt) {
                const int ro = (mt * 16 + col) * HSTR + kc * 32 + q * 8;
                ah[kc][mt] = *(const short8*)(Hhi + B1p + ro);
                al[kc][mt] = *(const short8*)(Hlo + B1p + ro);
            }
        f32x4 prc[2][2];
#pragma unroll
        for (int g2 = 0; g2 < 2; ++g2)
#pragma unroll
            for (int mt = 0; mt < 2; ++mt)
                prc[g2][mt] = (f32x4){biasMc[g2], biasMc[g2], biasMc[g2], biasMc[g2]};
#pragma unroll
        for (int g2 = 0; g2 < 2; ++g2)
#pragma unroll
            for (int mt = 0; mt < 2; ++mt) prc[g2][mt] = MFMA16(ah[0][mt], Whi[0][g2][0], prc[g2][mt]);
#pragma unroll
        for (int g2 = 0; g2 < 2; ++g2)
#pragma unroll
            for (int mt = 0; mt < 2; ++mt) prc[g2][mt] = MFMA16(ah[1][mt], Whi[0][g2][1], prc[g2][mt]);
#pragma unroll
        for (int g2 = 0; g2 < 2; ++g2)
#pragma unroll
            for (int mt = 0; mt < 2; ++mt) prc[g2][mt] = MFMA16(al[0][mt], Whi[0][g2][0], prc[g2][mt]);
#pragma unroll
        for (int g2 = 0; g2 < 2; ++g2)
#pragma unroll
            for (int mt = 0; mt < 2; ++mt) prc[g2][mt] = MFMA16(al[1][mt], Whi[0][g2][1], prc[g2][mt]);
#pragma unroll
        for (int g2 = 0; g2 < 2; ++g2)
#pragma unroll
            for (int mt = 0; mt < 2; ++mt)
#pragma unroll
                for (int r = 0; r < 4; ++r)
                    PRE[(2 * P + g2) * PG + (mt * 16 + q * 4 + r) * PSTR + U * 16 + col] = prc[g2][mt][r];
        __syncthreads();   // A

        {
            float pg[4][4];
#pragma unroll
            for (int g = 0; g < 4; ++g)
#pragma unroll
                for (int r = 0; r < 4; ++r)
                    pg[g][r] = PRE[g * PG + (me + r) * PSTR + uu];
#pragma unroll
            for (int r = 0; r < 4; ++r) {
                const float xw = ybufF[me + r];
                const float ig = sigm (pg[0][r] + xw * wcihgE[0]);
                const float fg = sigm (pg[1][r] + xw * wcihgE[1]);
                const float gt = tanh_(pg[2][r] + xw * wcihgE[2]);
                const float og = sigm (pg[3][r] + xw * wcihgE[3]);
                const float c  = fg * c1[r] + ig * gt;
                c1[r] = c;
                const float h  = og * tanh_(c);
                const short hb = f2b(h);
                const int  wi  = B1n + (me + r) * HSTR + uu;
                Hhi[wi] = hb;
                Hlo[wi] = f2b(h - b2f(hb));
            }
        }
        __syncthreads();   // B: h(new) ready

        if (tid < 32) {    // y = h @ W_out^T + b_out (exact f32 from hi+lo)
            const int m = tid;
            float s = boutF;
#pragma unroll
            for (int k = 0; k < 64; ++k)
                s += (b2f(Hhi[B1n + m * HSTR + k]) + b2f(Hlo[B1n + m * HSTR + k])) * woutF[k];
            outp[t * Sv + m] = s;
            ybufF[m] = s;
        }
        __syncthreads();   // C: ybufF ready for next step
    }
}

extern "C" void kernel_launch(void* const* d_in, const int* in_sizes, int n_in,
                              void* d_out, int out_size, void* d_ws, size_t ws_size,
                              hipStream_t stream)
{
    const float* x_seq = (const float*)d_in[0];
    const float* Wih0  = (const float*)d_in[1];
    const float* Whh0  = (const float*)d_in[2];
    const float* bih0  = (const float*)d_in[3];
    const float* bhh0  = (const float*)d_in[4];
    const float* Wih1  = (const float*)d_in[5];
    const float* Whh1  = (const float*)d_in[6];
    const float* bih1  = (const float*)d_in[7];
    const float* bhh1  = (const float*)d_in[8];
    const float* Wcih  = (const float*)d_in[9];
    const float* Wchh  = (const float*)d_in[10];
    const float* bcih  = (const float*)d_in[11];
    const float* bchh  = (const float*)d_in[12];
    const float* Wout  = (const float*)d_in[13];
    const float* bout  = (const float*)d_in[14];
    float* out = (float*)d_out;

    hipLaunchKernelGGL(sitewise_lstm, dim3(Bv * (Sv / 32)), dim3(512), 0, stream,
                       x_seq, Wih0, Whh0, bih0, bhh0, Wih1, Whh1, bih1, bhh1,
                       Wcih, Wchh, bcih, bchh, Wout, bout, out);
}

// Round 12
// 855.555 us; speedup vs baseline: 2.4603x; 1.4436x over previous
//
#include <hip/hip_runtime.h>

typedef __attribute__((ext_vector_type(8))) short short8;
typedef __attribute__((ext_vector_type(4))) float f32x4;

#define MFMA16(a, b, c) __builtin_amdgcn_mfma_f32_16x16x32_bf16((a), (b), (c), 0, 0, 0)

constexpr int Bv  = 32;    // batch
constexpr int Lv  = 168;   // encoder length
constexpr int Sv  = 512;   // sites
constexpr int HZv = 24;    // horizon
constexpr int Mv  = 64;    // sequences per block (one pass: 256 blocks)
constexpr int HSTR = 88;   // h-row stride (shorts)
constexpr int HBUF = Mv * HSTR;   // 5632 shorts per buffer

__device__ __forceinline__ float b2f(short s) {
    unsigned u = ((unsigned)(unsigned short)s) << 16;
    return __builtin_bit_cast(float, u);
}
__device__ __forceinline__ short f2b(float f) {
    unsigned u = __builtin_bit_cast(unsigned, f);
    unsigned r = (u + 0x7FFFu + ((u >> 16) & 1u)) >> 16;   // RNE
    return (short)(unsigned short)r;
}
__device__ __forceinline__ float sigm(float x) {
    x = fmaxf(x, -85.0f);
    float e = __builtin_amdgcn_exp2f(-1.44269504088896f * x);
    return __builtin_amdgcn_rcpf(1.0f + e);
}
__device__ __forceinline__ float tanh_(float x) {
    x = fminf(x, 43.0f);
    float e = __builtin_amdgcn_exp2f(2.88539008177793f * x); // exp(2x)
    return 1.0f - 2.0f * __builtin_amdgcn_rcpf(e + 1.0f);
}
__device__ __forceinline__ void hi8(const float* __restrict__ p, short8& hi) {
#pragma unroll
    for (int j = 0; j < 8; ++j) hi[j] = f2b(p[j]);
}

// 512-thread block (8 waves), M=64 seqs, 256 blocks = ONE pass (no 2-pass serialization).
// Wave wv: m-half mh=wv>>2 (m in [32mh,32mh+32)), unit-slice U=wv&3 (u in [16U,16U+16)),
// ALL 4 gates -> epilogue register-local: NO PRE exchange, 2 barriers/step.
// W single-bf16 (RNE, r11-validated), h hi+lo in LDS. LDS 90.6 KB -> 1 block/CU.
__global__ __launch_bounds__(512)
void sitewise_lstm(const float* __restrict__ x_seq,
                   const float* __restrict__ Wih0, const float* __restrict__ Whh0,
                   const float* __restrict__ bih0, const float* __restrict__ bhh0,
                   const float* __restrict__ Wih1, const float* __restrict__ Whh1,
                   const float* __restrict__ bih1, const float* __restrict__ bhh1,
                   const float* __restrict__ Wcih, const float* __restrict__ Wchh,
                   const float* __restrict__ bcih, const float* __restrict__ bchh,
                   const float* __restrict__ Wout, const float* __restrict__ bout,
                   float* __restrict__ out)
{
    __shared__ __align__(16) short Hhi[4 * HBUF];   // 45 KB: [layer*2+parity]
    __shared__ __align__(16) short Hlo[4 * HBUF];   // 45 KB
    __shared__ float woutF[64];
    __shared__ float ybufF[Mv];

    const int tid  = threadIdx.x;
    const int wv   = tid >> 6;
    const int lane = tid & 63;
    const int q    = lane >> 4;
    const int col  = lane & 15;
    const int mh   = wv >> 2;     // m-half: m in [32mh, 32mh+32)
    const int U    = wv & 3;      // unit-slice: u in [16U, 16U+16)
    const int bid  = blockIdx.x;
    const int b    = bid >> 3;
    const int s0   = (bid & 7) << 6;
    const int uu   = U * 16 + col;            // this lane's unit column
    const int me   = mh * 32 + q * 4;         // epilogue m base (+ mt*16 + r)

    for (int i = tid; i < 4 * HBUF / 2; i += 512) { ((int*)Hhi)[i] = 0; ((int*)Hlo)[i] = 0; }
    if (tid < 64) woutF[tid] = Wout[tid];

    const float* xbF = x_seq + b * Lv * Sv + s0;

    // ---- per-wave weights: 4 gate-tiles x 2 kc per matrix, single bf16 (RNE) ----
    short8 Whi[3][4][2];   // [Whh0|Wih1|Whh1][g][kc]; slot0 -> Wchh in decoder
    float bias0[4], bias1[4], biasc[4], wih0gE[4], wcihgE[4];
#pragma unroll
    for (int g = 0; g < 4; ++g) {
        const int j = g * 64 + U * 16 + col;
        bias0[g] = bih0[j] + bhh0[j];
        bias1[g] = bih1[j] + bhh1[j];
        biasc[g] = bcih[j] + bchh[j];
#pragma unroll
        for (int kc = 0; kc < 2; ++kc) {
            const int off = j * 64 + kc * 32 + q * 8;
            hi8(Whh0 + off, Whi[0][g][kc]);
            hi8(Wih1 + off, Whi[1][g][kc]);
            hi8(Whh1 + off, Whi[2][g][kc]);
        }
        wih0gE[g] = Wih0[g * 64 + uu];
        wcihgE[g] = Wcih[g * 64 + uu];
    }

    float c0[8], c1[8];
#pragma unroll
    for (int i = 0; i < 8; ++i) { c0[i] = 0.f; c1[i] = 0.f; }

    __syncthreads();

    // ================= encoder =================
    for (int t = 0; t < Lv; ++t) {
        const int p = t & 1, np = p ^ 1;
        const int B0p = p * HBUF, B0n = np * HBUF;
        const int B1p = (2 + p) * HBUF, B1n = (2 + np) * HBUF;

        // x for this wave's m rows (consumed in epilogue 0)
        f32x4 xv[2];
#pragma unroll
        for (int mt = 0; mt < 2; ++mt)
            xv[mt] = *(const f32x4*)(xbF + t * Sv + me + mt * 16);

        // ---- phase 1: L0 = (h0_hi + h0_lo) @ Whh0, this wave's m-tiles ----
        short8 ah[2][2], al[2][2];
#pragma unroll
        for (int kc = 0; kc < 2; ++kc)
#pragma unroll
            for (int mt = 0; mt < 2; ++mt) {
                const int ro = ((mh * 2 + mt) * 16 + col) * HSTR + kc * 32 + q * 8;
                ah[kc][mt] = *(const short8*)(Hhi + B0p + ro);
                al[kc][mt] = *(const short8*)(Hlo + B0p + ro);
            }
        f32x4 pre0[4][2];
#pragma unroll
        for (int g = 0; g < 4; ++g)
#pragma unroll
            for (int mt = 0; mt < 2; ++mt)
                pre0[g][mt] = (f32x4){bias0[g], bias0[g], bias0[g], bias0[g]};
#pragma unroll
        for (int g = 0; g < 4; ++g)
#pragma unroll
            for (int mt = 0; mt < 2; ++mt) pre0[g][mt] = MFMA16(ah[0][mt], Whi[0][g][0], pre0[g][mt]);
#pragma unroll
        for (int g = 0; g < 4; ++g)
#pragma unroll
            for (int mt = 0; mt < 2; ++mt) pre0[g][mt] = MFMA16(ah[1][mt], Whi[0][g][1], pre0[g][mt]);
#pragma unroll
        for (int g = 0; g < 4; ++g)
#pragma unroll
            for (int mt = 0; mt < 2; ++mt) pre0[g][mt] = MFMA16(al[0][mt], Whi[0][g][0], pre0[g][mt]);
#pragma unroll
        for (int g = 0; g < 4; ++g)
#pragma unroll
            for (int mt = 0; mt < 2; ++mt) pre0[g][mt] = MFMA16(al[1][mt], Whi[0][g][1], pre0[g][mt]);

        // ---- epilogue 0: register-local gates, write h0new ----
#pragma unroll
        for (int mt = 0; mt < 2; ++mt)
#pragma unroll
            for (int r = 0; r < 4; ++r) {
                const float xw = xv[mt][r];
                const float ig = sigm (pre0[0][mt][r] + xw * wih0gE[0]);
                const float fg = sigm (pre0[1][mt][r] + xw * wih0gE[1]);
                const float gt = tanh_(pre0[2][mt][r] + xw * wih0gE[2]);
                const float og = sigm (pre0[3][mt][r] + xw * wih0gE[3]);
                const float c  = fg * c0[mt * 4 + r] + ig * gt;
                c0[mt * 4 + r] = c;
                const float h  = og * tanh_(c);
                const short hb = f2b(h);
                const int  wi  = B0n + (me + mt * 16 + r) * HSTR + uu;
                Hhi[wi] = hb;
                Hlo[wi] = f2b(h - b2f(hb));
            }
        __syncthreads();   // barrier 1: h0(new) visible

        // ---- phase 2a: L1 h0-terms ----
        short8 bh[2][2], bl[2][2];
#pragma unroll
        for (int kc = 0; kc < 2; ++kc)
#pragma unroll
            for (int mt = 0; mt < 2; ++mt) {
                const int ro = ((mh * 2 + mt) * 16 + col) * HSTR + kc * 32 + q * 8;
                bh[kc][mt] = *(const short8*)(Hhi + B0n + ro);
                bl[kc][mt] = *(const short8*)(Hlo + B0n + ro);
            }
        f32x4 pre1[4][2];
#pragma unroll
        for (int g = 0; g < 4; ++g)
#pragma unroll
            for (int mt = 0; mt < 2; ++mt)
                pre1[g][mt] = (f32x4){bias1[g], bias1[g], bias1[g], bias1[g]};
#pragma unroll
        for (int g = 0; g < 4; ++g)
#pragma unroll
            for (int mt = 0; mt < 2; ++mt) pre1[g][mt] = MFMA16(bh[0][mt], Whi[1][g][0], pre1[g][mt]);
#pragma unroll
        for (int g = 0; g < 4; ++g)
#pragma unroll
            for (int mt = 0; mt < 2; ++mt) pre1[g][mt] = MFMA16(bh[1][mt], Whi[1][g][1], pre1[g][mt]);
#pragma unroll
        for (int g = 0; g < 4; ++g)
#pragma unroll
            for (int mt = 0; mt < 2; ++mt) pre1[g][mt] = MFMA16(bl[0][mt], Whi[1][g][0], pre1[g][mt]);
#pragma unroll
        for (int g = 0; g < 4; ++g)
#pragma unroll
            for (int mt = 0; mt < 2; ++mt) pre1[g][mt] = MFMA16(bl[1][mt], Whi[1][g][1], pre1[g][mt]);

        // ---- phase 2b: L1 h1-old terms (frags read late to cap VGPR peak) ----
        short8 dh[2][2], dl[2][2];
#pragma unroll
        for (int kc = 0; kc < 2; ++kc)
#pragma unroll
            for (int mt = 0; mt < 2; ++mt) {
                const int ro = ((mh * 2 + mt) * 16 + col) * HSTR + kc * 32 + q * 8;
                dh[kc][mt] = *(const short8*)(Hhi + B1p + ro);
                dl[kc][mt] = *(const short8*)(Hlo + B1p + ro);
            }
#pragma unroll
        for (int g = 0; g < 4; ++g)
#pragma unroll
            for (int mt = 0; mt < 2; ++mt) pre1[g][mt] = MFMA16(dh[0][mt], Whi[2][g][0], pre1[g][mt]);
#pragma unroll
        for (int g = 0; g < 4; ++g)
#pragma unroll
            for (int mt = 0; mt < 2; ++mt) pre1[g][mt] = MFMA16(dh[1][mt], Whi[2][g][1], pre1[g][mt]);
#pragma unroll
        for (int g = 0; g < 4; ++g)
#pragma unroll
            for (int mt = 0; mt < 2; ++mt) pre1[g][mt] = MFMA16(dl[0][mt], Whi[2][g][0], pre1[g][mt]);
#pragma unroll
        for (int g = 0; g < 4; ++g)
#pragma unroll
            for (int mt = 0; mt < 2; ++mt) pre1[g][mt] = MFMA16(dl[1][mt], Whi[2][g][1], pre1[g][mt]);

        // ---- epilogue 1: register-local, write h1new ----
#pragma unroll
        for (int mt = 0; mt < 2; ++mt)
#pragma unroll
            for (int r = 0; r < 4; ++r) {
                const float ig = sigm (pre1[0][mt][r]);
                const float fg = sigm (pre1[1][mt][r]);
                const float gt = tanh_(pre1[2][mt][r]);
                const float og = sigm (pre1[3][mt][r]);
                const float c  = fg * c1[mt * 4 + r] + ig * gt;
                c1[mt * 4 + r] = c;
                const float h  = og * tanh_(c);
                const short hb = f2b(h);
                const int  wi  = B1n + (me + mt * 16 + r) * HSTR + uu;
                Hhi[wi] = hb;
                Hlo[wi] = f2b(h - b2f(hb));
            }
        __syncthreads();   // barrier 2: state visible for next step
    }

    // ================= decoder =================
#pragma unroll
    for (int g = 0; g < 4; ++g)
#pragma unroll
        for (int kc = 0; kc < 2; ++kc)
            hi8(Wchh + (g * 64 + U * 16 + col) * 64 + kc * 32 + q * 8, Whi[0][g][kc]);
    if (tid < Mv) ybufF[tid] = xbF[(Lv - 1) * Sv + tid];
    __syncthreads();

    const float boutF = bout[0];
    float* outp = out + b * HZv * Sv + s0;

    for (int t = 0; t < HZv; ++t) {
        const int p = t & 1, np = p ^ 1;
        const int B1p = (2 + p) * HBUF, B1n = (2 + np) * HBUF;

        short8 ah[2][2], al[2][2];
#pragma unroll
        for (int kc = 0; kc < 2; ++kc)
#pragma unroll
            for (int mt = 0; mt < 2; ++mt) {
                const int ro = ((mh * 2 + mt) * 16 + col) * HSTR + kc * 32 + q * 8;
                ah[kc][mt] = *(const short8*)(Hhi + B1p + ro);
                al[kc][mt] = *(const short8*)(Hlo + B1p + ro);
            }
        float yv[2][4];
#pragma unroll
        for (int mt = 0; mt < 2; ++mt)
#pragma unroll
            for (int r = 0; r < 4; ++r)
                yv[mt][r] = ybufF[me + mt * 16 + r];

        f32x4 prc[4][2];
#pragma unroll
        for (int g = 0; g < 4; ++g)
#pragma unroll
            for (int mt = 0; mt < 2; ++mt)
                prc[g][mt] = (f32x4){biasc[g], biasc[g], biasc[g], biasc[g]};
#pragma unroll
        for (int g = 0; g < 4; ++g)
#pragma unroll
            for (int mt = 0; mt < 2; ++mt) prc[g][mt] = MFMA16(ah[0][mt], Whi[0][g][0], prc[g][mt]);
#pragma unroll
        for (int g = 0; g < 4; ++g)
#pragma unroll
            for (int mt = 0; mt < 2; ++mt) prc[g][mt] = MFMA16(ah[1][mt], Whi[0][g][1], prc[g][mt]);
#pragma unroll
        for (int g = 0; g < 4; ++g)
#pragma unroll
            for (int mt = 0; mt < 2; ++mt) prc[g][mt] = MFMA16(al[0][mt], Whi[0][g][0], prc[g][mt]);
#pragma unroll
        for (int g = 0; g < 4; ++g)
#pragma unroll
            for (int mt = 0; mt < 2; ++mt) prc[g][mt] = MFMA16(al[1][mt], Whi[0][g][1], prc[g][mt]);

#pragma unroll
        for (int mt = 0; mt < 2; ++mt)
#pragma unroll
            for (int r = 0; r < 4; ++r) {
                const float xw = yv[mt][r];
                const float ig = sigm (prc[0][mt][r] + xw * wcihgE[0]);
                const float fg = sigm (prc[1][mt][r] + xw * wcihgE[1]);
                const float gt = tanh_(prc[2][mt][r] + xw * wcihgE[2]);
                const float og = sigm (prc[3][mt][r] + xw * wcihgE[3]);
                const float c  = fg * c1[mt * 4 + r] + ig * gt;
                c1[mt * 4 + r] = c;
                const float h  = og * tanh_(c);
                const short hb = f2b(h);
                const int  wi  = B1n + (me + mt * 16 + r) * HSTR + uu;
                Hhi[wi] = hb;
                Hlo[wi] = f2b(h - b2f(hb));
            }
        __syncthreads();   // h(new) visible

        if (tid < Mv) {    // y = h @ W_out^T + b_out (exact f32 from hi+lo)
            const int m = tid;
            float s = boutF;
#pragma unroll
            for (int k = 0; k < 64; ++k)
                s += (b2f(Hhi[B1n + m * HSTR + k]) + b2f(Hlo[B1n + m * HSTR + k])) * woutF[k];
            outp[t * Sv + m] = s;
            ybufF[m] = s;
        }
        __syncthreads();   // ybufF ready for next step
    }
}

extern "C" void kernel_launch(void* const* d_in, const int* in_sizes, int n_in,
                              void* d_out, int out_size, void* d_ws, size_t ws_size,
                              hipStream_t stream)
{
    const float* x_seq = (const float*)d_in[0];
    const float* Wih0  = (const float*)d_in[1];
    const float* Whh0  = (const float*)d_in[2];
    const float* bih0  = (const float*)d_in[3];
    const float* bhh0  = (const float*)d_in[4];
    const float* Wih1  = (const float*)d_in[5];
    const float* Whh1  = (const float*)d_in[6];
    const float* bih1  = (const float*)d_in[7];
    const float* bhh1  = (const float*)d_in[8];
    const float* Wcih  = (const float*)d_in[9];
    const float* Wchh  = (const float*)d_in[10];
    const float* bcih  = (const float*)d_in[11];
    const float* bchh  = (const float*)d_in[12];
    const float* Wout  = (const float*)d_in[13];
    const float* bout  = (const float*)d_in[14];
    float* out = (float*)d_out;

    hipLaunchKernelGGL(sitewise_lstm, dim3(Bv * (Sv / Mv)), dim3(512), 0, stream,
                       x_seq, Wih0, Whh0, bih0, bhh0, Wih1, Whh1, bih1, bhh1,
                       Wcih, Wchh, bcih, bchh, Wout, bout, out);
}

// Round 13
// 685.291 us; speedup vs baseline: 3.0716x; 1.2485x over previous
//
#include <hip/hip_runtime.h>

typedef __attribute__((ext_vector_type(8))) short short8;
typedef __attribute__((ext_vector_type(4))) float f32x4;

#define MFMA16(a, b, c) __builtin_amdgcn_mfma_f32_16x16x32_bf16((a), (b), (c), 0, 0, 0)

constexpr int Bv  = 32;    // batch
constexpr int Lv  = 168;   // encoder length
constexpr int Sv  = 512;   // sites
constexpr int HZv = 24;    // horizon
constexpr int Mv  = 64;    // sequences per block (256 blocks = one pass)
constexpr int HSTR = 88;   // h-row stride (shorts)
constexpr int HBUF = Mv * HSTR;   // 5632 shorts per buffer

__device__ __forceinline__ float b2f(short s) {
    unsigned u = ((unsigned)(unsigned short)s) << 16;
    return __builtin_bit_cast(float, u);
}
__device__ __forceinline__ short f2b(float f) {
    unsigned u = __builtin_bit_cast(unsigned, f);
    unsigned r = (u + 0x7FFFu + ((u >> 16) & 1u)) >> 16;   // RNE
    return (short)(unsigned short)r;
}
__device__ __forceinline__ float sigm(float x) {
    x = fmaxf(x, -85.0f);
    float e = __builtin_amdgcn_exp2f(-1.44269504088896f * x);
    return __builtin_amdgcn_rcpf(1.0f + e);
}
__device__ __forceinline__ float tanh_(float x) {
    x = fminf(x, 43.0f);
    float e = __builtin_amdgcn_exp2f(2.88539008177793f * x); // exp(2x)
    return 1.0f - 2.0f * __builtin_amdgcn_rcpf(e + 1.0f);
}
__device__ __forceinline__ void hi8(const float* __restrict__ p, short8& hi) {
#pragma unroll
    for (int j = 0; j < 8; ++j) hi[j] = f2b(p[j]);
}

// r13: single-bf16 h state (lo plane dropped): halves MFMA/LDS/f2b vs r12.
// 512 threads (8 waves), M=64, 256 blocks = one pass. Wave: mh=wv>>2, U=wv&3,
// all 4 gates -> register-local epilogue, 2 barriers/step. LDS 45.6 KB.
// Loops unrolled x2 so LDS buffer offsets are immediates.
__global__ __launch_bounds__(512)
void sitewise_lstm(const float* __restrict__ x_seq,
                   const float* __restrict__ Wih0, const float* __restrict__ Whh0,
                   const float* __restrict__ bih0, const float* __restrict__ bhh0,
                   const float* __restrict__ Wih1, const float* __restrict__ Whh1,
                   const float* __restrict__ bih1, const float* __restrict__ bhh1,
                   const float* __restrict__ Wcih, const float* __restrict__ Wchh,
                   const float* __restrict__ bcih, const float* __restrict__ bchh,
                   const float* __restrict__ Wout, const float* __restrict__ bout,
                   float* __restrict__ out)
{
    __shared__ __align__(16) short Hhi[4 * HBUF];   // 45 KB: [layer*2+parity]
    __shared__ float woutF[64];
    __shared__ float ybufF[Mv];

    const int tid  = threadIdx.x;
    const int wv   = tid >> 6;
    const int lane = tid & 63;
    const int q    = lane >> 4;
    const int col  = lane & 15;
    const int mh   = wv >> 2;     // m-half: m in [32mh, 32mh+32)
    const int U    = wv & 3;      // unit-slice: u in [16U, 16U+16)
    const int bid  = blockIdx.x;
    const int b    = bid >> 3;
    const int s0   = (bid & 7) << 6;
    const int uu   = U * 16 + col;
    const int me   = mh * 32 + q * 4;         // epilogue m base (+ mt*16 + r)

    for (int i = tid; i < 4 * HBUF / 2; i += 512) ((int*)Hhi)[i] = 0;
    if (tid < 64) woutF[tid] = Wout[tid];

    const float* xbF = x_seq + b * Lv * Sv + s0;

    // fragment-read and h-write base offsets (buffer-relative; bases folded as imms)
    const int roA = ((mh * 2 + 0) * 16 + col) * HSTR + q * 8;   // + kc*32, + mt*512... mt stride = 16*HSTR
    const int wiA = (me) * HSTR + uu;                            // + (mt*16+r)*HSTR

    // ---- per-wave weights: 4 gate-tiles x 2 kc per matrix, single bf16 (RNE) ----
    short8 Whi[3][4][2];   // [Whh0|Wih1|Whh1][g][kc]; slot0 -> Wchh in decoder
    float bias0[4], bias1[4], biasc[4], wih0gE[4], wcihgE[4];
#pragma unroll
    for (int g = 0; g < 4; ++g) {
        const int j = g * 64 + U * 16 + col;
        bias0[g] = bih0[j] + bhh0[j];
        bias1[g] = bih1[j] + bhh1[j];
        biasc[g] = bcih[j] + bchh[j];
#pragma unroll
        for (int kc = 0; kc < 2; ++kc) {
            const int off = j * 64 + kc * 32 + q * 8;
            hi8(Whh0 + off, Whi[0][g][kc]);
            hi8(Wih1 + off, Whi[1][g][kc]);
            hi8(Whh1 + off, Whi[2][g][kc]);
        }
        wih0gE[g] = Wih0[g * 64 + uu];
        wcihgE[g] = Wcih[g * 64 + uu];
    }

    float c0[8], c1[8];
#pragma unroll
    for (int i = 0; i < 8; ++i) { c0[i] = 0.f; c1[i] = 0.f; }

    __syncthreads();

// one fused 2-layer encoder step; B0P/B0N/B1P/B1N are literal buffer bases
#define ENC_STEP(T, B0P, B0N, B1P, B1N) do {                                          \
        f32x4 xv[2];                                                                  \
        xv[0] = *(const f32x4*)(xbF + (T) * Sv + me);                                 \
        xv[1] = *(const f32x4*)(xbF + (T) * Sv + me + 16);                            \
        short8 ah[2][2];                                                              \
        _Pragma("unroll")                                                             \
        for (int kc = 0; kc < 2; ++kc)                                                \
            _Pragma("unroll")                                                         \
            for (int mt = 0; mt < 2; ++mt)                                            \
                ah[kc][mt] = *(const short8*)(Hhi + (B0P) + roA + kc * 32 + mt * 16 * HSTR); \
        f32x4 pre0[4][2];                                                             \
        _Pragma("unroll")                                                             \
        for (int g = 0; g < 4; ++g)                                                   \
            _Pragma("unroll")                                                         \
            for (int mt = 0; mt < 2; ++mt)                                            \
                pre0[g][mt] = (f32x4){bias0[g], bias0[g], bias0[g], bias0[g]};        \
        _Pragma("unroll")                                                             \
        for (int g = 0; g < 4; ++g)                                                   \
            _Pragma("unroll")                                                         \
            for (int mt = 0; mt < 2; ++mt) pre0[g][mt] = MFMA16(ah[0][mt], Whi[0][g][0], pre0[g][mt]); \
        _Pragma("unroll")                                                             \
        for (int g = 0; g < 4; ++g)                                                   \
            _Pragma("unroll")                                                         \
            for (int mt = 0; mt < 2; ++mt) pre0[g][mt] = MFMA16(ah[1][mt], Whi[0][g][1], pre0[g][mt]); \
        _Pragma("unroll")                                                             \
        for (int mt = 0; mt < 2; ++mt)                                                \
            _Pragma("unroll")                                                         \
            for (int r = 0; r < 4; ++r) {                                             \
                const float xw = xv[mt][r];                                           \
                const float ig = sigm (pre0[0][mt][r] + xw * wih0gE[0]);              \
                const float fg = sigm (pre0[1][mt][r] + xw * wih0gE[1]);              \
                const float gt = tanh_(pre0[2][mt][r] + xw * wih0gE[2]);              \
                const float og = sigm (pre0[3][mt][r] + xw * wih0gE[3]);              \
                const float c  = fg * c0[mt * 4 + r] + ig * gt;                       \
                c0[mt * 4 + r] = c;                                                   \
                Hhi[(B0N) + wiA + (mt * 16 + r) * HSTR] = f2b(og * tanh_(c));         \
            }                                                                         \
        __syncthreads();                                                              \
        short8 bh[2][2], dh[2][2];                                                    \
        _Pragma("unroll")                                                             \
        for (int kc = 0; kc < 2; ++kc)                                                \
            _Pragma("unroll")                                                         \
            for (int mt = 0; mt < 2; ++mt) {                                          \
                bh[kc][mt] = *(const short8*)(Hhi + (B0N) + roA + kc * 32 + mt * 16 * HSTR); \
                dh[kc][mt] = *(const short8*)(Hhi + (B1P) + roA + kc * 32 + mt * 16 * HSTR); \
            }                                                                         \
        f32x4 pre1[4][2];                                                             \
        _Pragma("unroll")                                                             \
        for (int g = 0; g < 4; ++g)                                                   \
            _Pragma("unroll")                                                         \
            for (int mt = 0; mt < 2; ++mt)                                            \
                pre1[g][mt] = (f32x4){bias1[g], bias1[g], bias1[g], bias1[g]};        \
        _Pragma("unroll")                                                             \
        for (int g = 0; g < 4; ++g)                                                   \
            _Pragma("unroll")                                                         \
            for (int mt = 0; mt < 2; ++mt) pre1[g][mt] = MFMA16(bh[0][mt], Whi[1][g][0], pre1[g][mt]); \
        _Pragma("unroll")                                                             \
        for (int g = 0; g < 4; ++g)                                                   \
            _Pragma("unroll")                                                         \
            for (int mt = 0; mt < 2; ++mt) pre1[g][mt] = MFMA16(bh[1][mt], Whi[1][g][1], pre1[g][mt]); \
        _Pragma("unroll")                                                             \
        for (int g = 0; g < 4; ++g)                                                   \
            _Pragma("unroll")                                                         \
            for (int mt = 0; mt < 2; ++mt) pre1[g][mt] = MFMA16(dh[0][mt], Whi[2][g][0], pre1[g][mt]); \
        _Pragma("unroll")                                                             \
        for (int g = 0; g < 4; ++g)                                                   \
            _Pragma("unroll")                                                         \
            for (int mt = 0; mt < 2; ++mt) pre1[g][mt] = MFMA16(dh[1][mt], Whi[2][g][1], pre1[g][mt]); \
        _Pragma("unroll")                                                             \
        for (int mt = 0; mt < 2; ++mt)                                                \
            _Pragma("unroll")                                                         \
            for (int r = 0; r < 4; ++r) {                                             \
                const float ig = sigm (pre1[0][mt][r]);                               \
                const float fg = sigm (pre1[1][mt][r]);                               \
                const float gt = tanh_(pre1[2][mt][r]);                               \
                const float og = sigm (pre1[3][mt][r]);                               \
                const float c  = fg * c1[mt * 4 + r] + ig * gt;                       \
                c1[mt * 4 + r] = c;                                                   \
                Hhi[(B1N) + wiA + (mt * 16 + r) * HSTR] = f2b(og * tanh_(c));         \
            }                                                                         \
        __syncthreads();                                                              \
    } while (0)

    // ================= encoder (unrolled x2: buffer bases are literals) =================
    for (int t = 0; t < Lv; t += 2) {
        ENC_STEP(t,     0 * HBUF, 1 * HBUF, 2 * HBUF, 3 * HBUF);
        ENC_STEP(t + 1, 1 * HBUF, 0 * HBUF, 3 * HBUF, 2 * HBUF);
    }
#undef ENC_STEP

    // ================= decoder =================
#pragma unroll
    for (int g = 0; g < 4; ++g)
#pragma unroll
        for (int kc = 0; kc < 2; ++kc)
            hi8(Wchh + (g * 64 + U * 16 + col) * 64 + kc * 32 + q * 8, Whi[0][g][kc]);
    if (tid < Mv) ybufF[tid] = xbF[(Lv - 1) * Sv + tid];
    __syncthreads();

    const float boutF = bout[0];
    float* outp = out + b * HZv * Sv + s0;

#define DEC_STEP(T, B1P, B1N) do {                                                    \
        short8 ah[2][2];                                                              \
        _Pragma("unroll")                                                             \
        for (int kc = 0; kc < 2; ++kc)                                                \
            _Pragma("unroll")                                                         \
            for (int mt = 0; mt < 2; ++mt)                                            \
                ah[kc][mt] = *(const short8*)(Hhi + (B1P) + roA + kc * 32 + mt * 16 * HSTR); \
        float yv[2][4];                                                               \
        _Pragma("unroll")                                                             \
        for (int mt = 0; mt < 2; ++mt)                                                \
            _Pragma("unroll")                                                         \
            for (int r = 0; r < 4; ++r)                                               \
                yv[mt][r] = ybufF[me + mt * 16 + r];                                  \
        f32x4 prc[4][2];                                                              \
        _Pragma("unroll")                                                             \
        for (int g = 0; g < 4; ++g)                                                   \
            _Pragma("unroll")                                                         \
            for (int mt = 0; mt < 2; ++mt)                                            \
                prc[g][mt] = (f32x4){biasc[g], biasc[g], biasc[g], biasc[g]};         \
        _Pragma("unroll")                                                             \
        for (int g = 0; g < 4; ++g)                                                   \
            _Pragma("unroll")                                                         \
            for (int mt = 0; mt < 2; ++mt) prc[g][mt] = MFMA16(ah[0][mt], Whi[0][g][0], prc[g][mt]); \
        _Pragma("unroll")                                                             \
        for (int g = 0; g < 4; ++g)                                                   \
            _Pragma("unroll")                                                         \
            for (int mt = 0; mt < 2; ++mt) prc[g][mt] = MFMA16(ah[1][mt], Whi[0][g][1], prc[g][mt]); \
        _Pragma("unroll")                                                             \
        for (int mt = 0; mt < 2; ++mt)                                                \
            _Pragma("unroll")                                                         \
            for (int r = 0; r < 4; ++r) {                                             \
                const float xw = yv[mt][r];                                           \
                const float ig = sigm (prc[0][mt][r] + xw * wcihgE[0]);               \
                const float fg = sigm (prc[1][mt][r] + xw * wcihgE[1]);               \
                const float gt = tanh_(prc[2][mt][r] + xw * wcihgE[2]);               \
                const float og = sigm (prc[3][mt][r] + xw * wcihgE[3]);               \
                const float c  = fg * c1[mt * 4 + r] + ig * gt;                       \
                c1[mt * 4 + r] = c;                                                   \
                Hhi[(B1N) + wiA + (mt * 16 + r) * HSTR] = f2b(og * tanh_(c));         \
            }                                                                         \
        __syncthreads();                                                              \
        if (tid < Mv) {                                                               \
            const int m = tid;                                                        \
            float s = boutF;                                                          \
            _Pragma("unroll")                                                         \
            for (int k = 0; k < 64; ++k)                                              \
                s += b2f(Hhi[(B1N) + m * HSTR + k]) * woutF[k];                       \
            outp[(T) * Sv + m] = s;                                                   \
            ybufF[m] = s;                                                             \
        }                                                                             \
        __syncthreads();                                                              \
    } while (0)

    for (int t = 0; t < HZv; t += 2) {
        DEC_STEP(t,     2 * HBUF, 3 * HBUF);
        DEC_STEP(t + 1, 3 * HBUF, 2 * HBUF);
    }
#undef DEC_STEP
}

extern "C" void kernel_launch(void* const* d_in, const int* in_sizes, int n_in,
                              void* d_out, int out_size, void* d_ws, size_t ws_size,
                              hipStream_t stream)
{
    const float* x_seq = (const float*)d_in[0];
    const float* Wih0  = (const float*)d_in[1];
    const float* Whh0  = (const float*)d_in[2];
    const float* bih0  = (const float*)d_in[3];
    const float* bhh0  = (const float*)d_in[4];
    const float* Wih1  = (const float*)d_in[5];
    const float* Whh1  = (const float*)d_in[6];
    const float* bih1  = (const float*)d_in[7];
    const float* bhh1  = (const float*)d_in[8];
    const float* Wcih  = (const float*)d_in[9];
    const float* Wchh  = (const float*)d_in[10];
    const float* bcih  = (const float*)d_in[11];
    const float* bchh  = (const float*)d_in[12];
    const float* Wout  = (const float*)d_in[13];
    const float* bout  = (const float*)d_in[14];
    float* out = (float*)d_out;

    hipLaunchKernelGGL(sitewise_lstm, dim3(Bv * (Sv / Mv)), dim3(512), 0, stream,
                       x_seq, Wih0, Whh0, bih0, bhh0, Wih1, Whh1, bih1, bhh1,
                       Wcih, Wchh, bcih, bchh, Wout, bout, out);
}

// Round 14
// 623.194 us; speedup vs baseline: 3.3776x; 1.0996x over previous
//
#include <hip/hip_runtime.h>

typedef __attribute__((ext_vector_type(8))) short short8;
typedef __attribute__((ext_vector_type(4))) float f32x4;

#define MFMA16(a, b, c) __builtin_amdgcn_mfma_f32_16x16x32_bf16((a), (b), (c), 0, 0, 0)

constexpr int Bv  = 32;    // batch
constexpr int Lv  = 168;   // encoder length
constexpr int Sv  = 512;   // sites
constexpr int HZv = 24;    // horizon
constexpr int Mv  = 64;    // sequences per block (256 blocks = one pass)
constexpr int HSTR = 88;   // h-row stride (shorts)
constexpr int HBUF = Mv * HSTR;   // 5632 shorts per buffer

__device__ __forceinline__ float b2f(short s) {
    unsigned u = ((unsigned)(unsigned short)s) << 16;
    return __builtin_bit_cast(float, u);
}
__device__ __forceinline__ short f2b(float f) {
    unsigned u = __builtin_bit_cast(unsigned, f);
    unsigned r = (u + 0x7FFFu + ((u >> 16) & 1u)) >> 16;   // RNE
    return (short)(unsigned short)r;
}
// no clamps: exp2(inf)=inf, rcp(inf)=0 give exact saturation, no NaN path
__device__ __forceinline__ float sigm(float x) {
    float e = __builtin_amdgcn_exp2f(-1.44269504088896f * x);
    return __builtin_amdgcn_rcpf(1.0f + e);
}
__device__ __forceinline__ float tanh_(float x) {
    float e = __builtin_amdgcn_exp2f(2.88539008177793f * x); // exp(2x)
    return 1.0f - 2.0f * __builtin_amdgcn_rcpf(e + 1.0f);
}
__device__ __forceinline__ void hi8(const float* __restrict__ p, short8& hi) {
#pragma unroll
    for (int j = 0; j < 8; ++j) hi[j] = f2b(p[j]);
}

// r14: ONE barrier per encoder step (hazard-audited: phase1 reads only B0p;
// B1 reads sit after barrier; all cross-step RAW/WAR pairs are separated by
// exactly one barrier). Single-bf16 h state, M=64, 256 blocks = one pass.
__global__ __launch_bounds__(512)
void sitewise_lstm(const float* __restrict__ x_seq,
                   const float* __restrict__ Wih0, const float* __restrict__ Whh0,
                   const float* __restrict__ bih0, const float* __restrict__ bhh0,
                   const float* __restrict__ Wih1, const float* __restrict__ Whh1,
                   const float* __restrict__ bih1, const float* __restrict__ bhh1,
                   const float* __restrict__ Wcih, const float* __restrict__ Wchh,
                   const float* __restrict__ bcih, const float* __restrict__ bchh,
                   const float* __restrict__ Wout, const float* __restrict__ bout,
                   float* __restrict__ out)
{
    __shared__ __align__(16) short Hhi[4 * HBUF];   // 45 KB: [layer*2+parity]
    __shared__ float woutF[64];
    __shared__ float ybufF[Mv];

    const int tid  = threadIdx.x;
    const int wv   = tid >> 6;
    const int lane = tid & 63;
    const int q    = lane >> 4;
    const int col  = lane & 15;
    const int mh   = wv >> 2;     // m-half: m in [32mh, 32mh+32)
    const int U    = wv & 3;      // unit-slice: u in [16U, 16U+16)
    const int bid  = blockIdx.x;
    const int b    = bid >> 3;
    const int s0   = (bid & 7) << 6;
    const int uu   = U * 16 + col;
    const int me   = mh * 32 + q * 4;         // epilogue m base (+ mt*16 + r)

    for (int i = tid; i < 4 * HBUF / 2; i += 512) ((int*)Hhi)[i] = 0;
    if (tid < 64) woutF[tid] = Wout[tid];

    const float* xbF = x_seq + b * Lv * Sv + s0;

    const int roA = ((mh * 2 + 0) * 16 + col) * HSTR + q * 8;   // + kc*32 + mt*16*HSTR
    const int wiA = (me) * HSTR + uu;                            // + (mt*16+r)*HSTR

    // ---- per-wave weights: 4 gate-tiles x 2 kc per matrix, single bf16 (RNE) ----
    short8 Whi[3][4][2];   // [Whh0|Wih1|Whh1][g][kc]; slot0 -> Wchh in decoder
    float bias0[4], bias1[4], biasc[4], wih0gE[4], wcihgE[4];
#pragma unroll
    for (int g = 0; g < 4; ++g) {
        const int j = g * 64 + U * 16 + col;
        bias0[g] = bih0[j] + bhh0[j];
        bias1[g] = bih1[j] + bhh1[j];
        biasc[g] = bcih[j] + bchh[j];
#pragma unroll
        for (int kc = 0; kc < 2; ++kc) {
            const int off = j * 64 + kc * 32 + q * 8;
            hi8(Whh0 + off, Whi[0][g][kc]);
            hi8(Wih1 + off, Whi[1][g][kc]);
            hi8(Whh1 + off, Whi[2][g][kc]);
        }
        wih0gE[g] = Wih0[g * 64 + uu];
        wcihgE[g] = Wcih[g * 64 + uu];
    }

    float c0[8], c1[8];
#pragma unroll
    for (int i = 0; i < 8; ++i) { c0[i] = 0.f; c1[i] = 0.f; }

    __syncthreads();

// one fused 2-layer encoder step, ONE barrier; buffer bases are literals
#define ENC_STEP(T, B0P, B0N, B1P, B1N) do {                                          \
        f32x4 xv[2];                                                                  \
        xv[0] = *(const f32x4*)(xbF + (T) * Sv + me);                                 \
        xv[1] = *(const f32x4*)(xbF + (T) * Sv + me + 16);                            \
        short8 ah[2][2];                                                              \
        _Pragma("unroll")                                                             \
        for (int kc = 0; kc < 2; ++kc)                                                \
            _Pragma("unroll")                                                         \
            for (int mt = 0; mt < 2; ++mt)                                            \
                ah[kc][mt] = *(const short8*)(Hhi + (B0P) + roA + kc * 32 + mt * 16 * HSTR); \
        f32x4 pre0[4][2];                                                             \
        _Pragma("unroll")                                                             \
        for (int g = 0; g < 4; ++g)                                                   \
            _Pragma("unroll")                                                         \
            for (int mt = 0; mt < 2; ++mt)                                            \
                pre0[g][mt] = (f32x4){bias0[g], bias0[g], bias0[g], bias0[g]};        \
        _Pragma("unroll")                                                             \
        for (int g = 0; g < 4; ++g)                                                   \
            _Pragma("unroll")                                                         \
            for (int mt = 0; mt < 2; ++mt) pre0[g][mt] = MFMA16(ah[0][mt], Whi[0][g][0], pre0[g][mt]); \
        _Pragma("unroll")                                                             \
        for (int g = 0; g < 4; ++g)                                                   \
            _Pragma("unroll")                                                         \
            for (int mt = 0; mt < 2; ++mt) pre0[g][mt] = MFMA16(ah[1][mt], Whi[0][g][1], pre0[g][mt]); \
        _Pragma("unroll")                                                             \
        for (int mt = 0; mt < 2; ++mt)                                                \
            _Pragma("unroll")                                                         \
            for (int r = 0; r < 4; ++r) {                                             \
                const float xw = xv[mt][r];                                           \
                const float ig = sigm (pre0[0][mt][r] + xw * wih0gE[0]);              \
                const float fg = sigm (pre0[1][mt][r] + xw * wih0gE[1]);              \
                const float gt = tanh_(pre0[2][mt][r] + xw * wih0gE[2]);              \
                const float og = sigm (pre0[3][mt][r] + xw * wih0gE[3]);              \
                const float c  = fg * c0[mt * 4 + r] + ig * gt;                       \
                c0[mt * 4 + r] = c;                                                   \
                Hhi[(B0N) + wiA + (mt * 16 + r) * HSTR] = f2b(og * tanh_(c));         \
            }                                                                         \
        __syncthreads();   /* the ONLY barrier: h0(new) visible */                    \
        short8 bh[2][2], dh[2][2];                                                    \
        _Pragma("unroll")                                                             \
        for (int kc = 0; kc < 2; ++kc)                                                \
            _Pragma("unroll")                                                         \
            for (int mt = 0; mt < 2; ++mt) {                                          \
                bh[kc][mt] = *(const short8*)(Hhi + (B0N) + roA + kc * 32 + mt * 16 * HSTR); \
                dh[kc][mt] = *(const short8*)(Hhi + (B1P) + roA + kc * 32 + mt * 16 * HSTR); \
            }                                                                         \
        f32x4 pre1[4][2];                                                             \
        _Pragma("unroll")                                                             \
        for (int g = 0; g < 4; ++g)                                                   \
            _Pragma("unroll")                                                         \
            for (int mt = 0; mt < 2; ++mt)                                            \
                pre1[g][mt] = (f32x4){bias1[g], bias1[g], bias1[g], bias1[g]};        \
        _Pragma("unroll")                                                             \
        for (int g = 0; g < 4; ++g)                                                   \
            _Pragma("unroll")                                                         \
            for (int mt = 0; mt < 2; ++mt) pre1[g][mt] = MFMA16(bh[0][mt], Whi[1][g][0], pre1[g][mt]); \
        _Pragma("unroll")                                                             \
        for (int g = 0; g < 4; ++g)                                                   \
            _Pragma("unroll")                                                         \
            for (int mt = 0; mt < 2; ++mt) pre1[g][mt] = MFMA16(bh[1][mt], Whi[1][g][1], pre1[g][mt]); \
        _Pragma("unroll")                                                             \
        for (int g = 0; g < 4; ++g)                                                   \
            _Pragma("unroll")                                                         \
            for (int mt = 0; mt < 2; ++mt) pre1[g][mt] = MFMA16(dh[0][mt], Whi[2][g][0], pre1[g][mt]); \
        _Pragma("unroll")                                                             \
        for (int g = 0; g < 4; ++g)                                                   \
            _Pragma("unroll")                                                         \
            for (int mt = 0; mt < 2; ++mt) pre1[g][mt] = MFMA16(dh[1][mt], Whi[2][g][1], pre1[g][mt]); \
        _Pragma("unroll")                                                             \
        for (int mt = 0; mt < 2; ++mt)                                                \
            _Pragma("unroll")                                                         \
            for (int r = 0; r < 4; ++r) {                                             \
                const float ig = sigm (pre1[0][mt][r]);                               \
                const float fg = sigm (pre1[1][mt][r]);                               \
                const float gt = tanh_(pre1[2][mt][r]);                               \
                const float og = sigm (pre1[3][mt][r]);                               \
                const float c  = fg * c1[mt * 4 + r] + ig * gt;                       \
                c1[mt * 4 + r] = c;                                                   \
                Hhi[(B1N) + wiA + (mt * 16 + r) * HSTR] = f2b(og * tanh_(c));         \
            }                                                                         \
        /* no barrier 2: h1new visibility is provided by next step's barrier,  */     \
        /* which sits before the only B1n reader (next phase 2b)               */     \
    } while (0)

    for (int t = 0; t < Lv; t += 2) {
        ENC_STEP(t,     0 * HBUF, 1 * HBUF, 2 * HBUF, 3 * HBUF);
        ENC_STEP(t + 1, 1 * HBUF, 0 * HBUF, 3 * HBUF, 2 * HBUF);
    }
#undef ENC_STEP

    // ================= decoder =================
#pragma unroll
    for (int g = 0; g < 4; ++g)
#pragma unroll
        for (int kc = 0; kc < 2; ++kc)
            hi8(Wchh + (g * 64 + U * 16 + col) * 64 + kc * 32 + q * 8, Whi[0][g][kc]);
    if (tid < Mv) ybufF[tid] = xbF[(Lv - 1) * Sv + tid];
    __syncthreads();   // h1(final) + ybufF visible

    const float boutF = bout[0];
    float* outp = out + b * HZv * Sv + s0;

#define DEC_STEP(T, B1P, B1N) do {                                                    \
        short8 ah[2][2];                                                              \
        _Pragma("unroll")                                                             \
        for (int kc = 0; kc < 2; ++kc)                                                \
            _Pragma("unroll")                                                         \
            for (int mt = 0; mt < 2; ++mt)                                            \
                ah[kc][mt] = *(const short8*)(Hhi + (B1P) + roA + kc * 32 + mt * 16 * HSTR); \
        float yv[2][4];                                                               \
        _Pragma("unroll")                                                             \
        for (int mt = 0; mt < 2; ++mt)                                                \
            _Pragma("unroll")                                                         \
            for (int r = 0; r < 4; ++r)                                               \
                yv[mt][r] = ybufF[me + mt * 16 + r];                                  \
        f32x4 prc[4][2];                                                              \
        _Pragma("unroll")                                                             \
        for (int g = 0; g < 4; ++g)                                                   \
            _Pragma("unroll")                                                         \
            for (int mt = 0; mt < 2; ++mt)                                            \
                prc[g][mt] = (f32x4){biasc[g], biasc[g], biasc[g], biasc[g]};         \
        _Pragma("unroll")                                                             \
        for (int g = 0; g < 4; ++g)                                                   \
            _Pragma("unroll")                                                         \
            for (int mt = 0; mt < 2; ++mt) prc[g][mt] = MFMA16(ah[0][mt], Whi[0][g][0], prc[g][mt]); \
        _Pragma("unroll")                                                             \
        for (int g = 0; g < 4; ++g)                                                   \
            _Pragma("unroll")                                                         \
            for (int mt = 0; mt < 2; ++mt) prc[g][mt] = MFMA16(ah[1][mt], Whi[0][g][1], prc[g][mt]); \
        _Pragma("unroll")                                                             \
        for (int mt = 0; mt < 2; ++mt)                                                \
            _Pragma("unroll")                                                         \
            for (int r = 0; r < 4; ++r) {                                             \
                const float xw = yv[mt][r];                                           \
                const float ig = sigm (prc[0][mt][r] + xw * wcihgE[0]);               \
                const float fg = sigm (prc[1][mt][r] + xw * wcihgE[1]);               \
                const float gt = tanh_(prc[2][mt][r] + xw * wcihgE[2]);               \
                const float og = sigm (prc[3][mt][r] + xw * wcihgE[3]);               \
                const float c  = fg * c1[mt * 4 + r] + ig * gt;                       \
                c1[mt * 4 + r] = c;                                                   \
                Hhi[(B1N) + wiA + (mt * 16 + r) * HSTR] = f2b(og * tanh_(c));         \
            }                                                                         \
        __syncthreads();                                                              \
        if (tid < Mv) {                                                               \
            const int m = tid;                                                        \
            float s = boutF;                                                          \
            _Pragma("unroll")                                                         \
            for (int k = 0; k < 64; ++k)                                              \
                s += b2f(Hhi[(B1N) + m * HSTR + k]) * woutF[k];                       \
            outp[(T) * Sv + m] = s;                                                   \
            ybufF[m] = s;                                                             \
        }                                                                             \
        __syncthreads();                                                              \
    } while (0)

    for (int t = 0; t < HZv; t += 2) {
        DEC_STEP(t,     2 * HBUF, 3 * HBUF);
        DEC_STEP(t + 1, 3 * HBUF, 2 * HBUF);
    }
#undef DEC_STEP
}

extern "C" void kernel_launch(void* const* d_in, const int* in_sizes, int n_in,
                              void* d_out, int out_size, void* d_ws, size_t ws_size,
                              hipStream_t stream)
{
    const float* x_seq = (const float*)d_in[0];
    const float* Wih0  = (const float*)d_in[1];
    const float* Whh0  = (const float*)d_in[2];
    const float* bih0  = (const float*)d_in[3];
    const float* bhh0  = (const float*)d_in[4];
    const float* Wih1  = (const float*)d_in[5];
    const float* Whh1  = (const float*)d_in[6];
    const float* bih1  = (const float*)d_in[7];
    const float* bhh1  = (const float*)d_in[8];
    const float* Wcih  = (const float*)d_in[9];
    const float* Wchh  = (const float*)d_in[10];
    const float* bcih  = (const float*)d_in[11];
    const float* bchh  = (const float*)d_in[12];
    const float* Wout  = (const float*)d_in[13];
    const float* bout  = (const float*)d_in[14];
    float* out = (float*)d_out;

    hipLaunchKernelGGL(sitewise_lstm, dim3(Bv * (Sv / Mv)), dim3(512), 0, stream,
                       x_seq, Wih0, Whh0, bih0, bhh0, Wih1, Whh1, bih1, bhh1,
                       Wcih, Wchh, bcih, bchh, Wout, bout, out);
}